// Round 4
// baseline (643.925 us; speedup 1.0000x reference)
//
#include <hip/hip_runtime.h>

typedef unsigned short u16;
typedef __attribute__((ext_vector_type(8))) short short8;
typedef __attribute__((ext_vector_type(4))) float f32x4;

#define SHIFT_ 4

__device__ __forceinline__ float bf2f(u16 u) {
  unsigned x = ((unsigned)u) << 16;
  return __builtin_bit_cast(float, x);
}
__device__ __forceinline__ u16 f2bf(float f) {
  unsigned u = __builtin_bit_cast(unsigned, f);
  u += 0x7fffu + ((u >> 16) & 1u);
  return (u16)(u >> 16);
}
__device__ __forceinline__ short8 ld8(const u16* p) {
  return *(const short8*)p;
}
__device__ __forceinline__ void gld16(const void* g, void* l) {
  __builtin_amdgcn_global_load_lds(
      (const __attribute__((address_space(1))) unsigned int*)g,
      (__attribute__((address_space(3))) unsigned int*)l, 16, 0, 0);
}
// lean tanh-gelu (exp + rcp form)
__device__ __forceinline__ float gelu_t(float x) {
  float x2 = x * x;
  float u = x * (0.7978845608028654f + 0.0356774081f * x2);
  float t = __expf(u + u);
  float th = 1.f - 2.f * __builtin_amdgcn_rcpf(t + 1.f);
  return 0.5f * x * (1.f + th);
}
__device__ __forceinline__ void barx() {
  asm volatile("" ::: "memory");
  __builtin_amdgcn_s_barrier();
  asm volatile("" ::: "memory");
}

// ---------------- transpose + fp32->bf16 convert (R x C fp32 -> C x R bf16) --
__global__ void transp(const float* __restrict__ in, u16* __restrict__ out, int R, int C) {
  __shared__ u16 t[32][33];
  int tx = threadIdx.x & 31, ty = threadIdx.x >> 5;
  int c0 = blockIdx.x * 32, r0 = blockIdx.y * 32;
#pragma unroll
  for (int i = 0; i < 4; i++)
    t[ty + i * 8][tx] = f2bf(in[(size_t)(r0 + ty + i * 8) * C + c0 + tx]);
  __syncthreads();
#pragma unroll
  for (int i = 0; i < 4; i++)
    out[(size_t)(c0 + ty + i * 8) * R + r0 + tx] = t[tx][ty + i * 8];
}

__global__ void concat_bias(const float* __restrict__ a, const float* __restrict__ b,
                            const float* __restrict__ c, float* __restrict__ o) {
  int i = blockIdx.x * 256 + threadIdx.x;
  if (i < 512) o[i] = a[i];
  else if (i < 1024) o[i] = b[i - 512];
  else if (i < 1536) o[i] = c[i - 1024];
}

// ---------------- LayerNorm fp32 -> bf16 (optionally fused shift+window) -----
__global__ void ln_win(const float* __restrict__ hid, const float* __restrict__ g,
                       const float* __restrict__ b, u16* __restrict__ out, int windowed) {
  int wv = threadIdx.x >> 6, lane = threadIdx.x & 63;
  int tokid = blockIdx.x * 4 + wv;
  size_t src;
  if (windowed) {
    int t = tokid & 63, w = tokid >> 6;
    int winin = w & 63, bb = w >> 6;
    int r = ((winin >> 3) * 8 + (t >> 3) + SHIFT_) & 63;
    int c = ((winin & 7) * 8 + (t & 7) + SHIFT_) & 63;
    src = ((size_t)bb * 4096 + r * 64 + c) * 512;
  } else {
    src = (size_t)tokid * 512;
  }
  f32x4 x0 = *(const f32x4*)(hid + src + lane * 8);
  f32x4 x1 = *(const f32x4*)(hid + src + lane * 8 + 4);
  float x[8];
#pragma unroll
  for (int e = 0; e < 4; e++) { x[e] = x0[e]; x[e + 4] = x1[e]; }
  float s = 0.f, s2 = 0.f;
#pragma unroll
  for (int e = 0; e < 8; e++) {
    s += x[e];
    s2 += x[e] * x[e];
  }
#pragma unroll
  for (int m = 1; m < 64; m <<= 1) {
    s += __shfl_xor(s, m);
    s2 += __shfl_xor(s2, m);
  }
  float mean = s * (1.f / 512.f);
  float var = s2 * (1.f / 512.f) - mean * mean;
  float rstd = rsqrtf(var + 1e-5f);
  u16 pack[8];
#pragma unroll
  for (int e = 0; e < 8; e++) {
    int c = lane * 8 + e;
    float y = (x[e] - mean) * rstd * g[c] + b[c];
    pack[e] = f2bf(y);
  }
  *(short8*)(out + (size_t)tokid * 512 + lane * 8) = *(const short8*)pack;
}

// ---------------- GEMM: C = A(MxK) @ Bt^T + bias, Bt is (N x K) bf16 --------
// 256x256 tile, BK=64, 512 threads = 8 waves (2M x 4N), per-wave 128x64
// (acc[8][4]). LDS 128KB = 2 K-tile buffers. Slot swizzle (slot_raw+(row>>1))&3
// -> ds_read_b128 2-way (free); staged via pre-swizzled global source +
// linear global_load_lds dest.
// 3 windows per K-tile, ONE barrier each (overlap version of the r3 schedule):
//  W1: stage B1(t+1) | read aF(8)+b0f(4)+b1f(4) | 32 MFMA quads (0,0),(0,1)
//  W2: stage B0(t+2) | read aF'(8) (rows+64)    | 16 MFMA quad (1,1)
//  W3: stage A0(t+2)+A1(t+2)                    | 16 MFMA quad (1,0)
//      + gate vmcnt(6) + barrier (tile t+1 resident, collective)
// NO blanket lgkmcnt(0): reads are plain loads, compiler emits counted
// lgkmcnt per consuming MFMA -> LDS drain overlaps the MFMA cluster.
// Race-freedom: a read issued in window W is consumed by W's MFMAs, hence
// retired before that wave passes W's end barrier. Stage targets:
//  - B(t+2,0) in W2: all B reads of buffer t&1 happen in W1 -> safe after B1end
//  - A(t+2,*) in W3: A reads end in W2 -> safe after W2end
//  - B(t+1,1) in W1: other buffer, last read in tile t-1's W1, 3 barriers back
// vmcnt gate: per tile 8 loads issued (W1:2, W2:2, W3:4); at the gate the
// newest 6 (W2+W3 stages) stay in flight, everything through B(t+1,1)
// retires -> tile t+1 fully resident. Tail: t+2>=kiter skips stages, last
// gate (t+2==kiter) uses vmcnt(0).
// epi 0: head-major QKV  | epi 1: window-reverse+unshift + residual (fp32)
// epi 2: bf16(gelu(val)) | epi 3: outf = resf + val (fp32)
__global__ __launch_bounds__(512, 2) void gemm_bt(
    const u16* __restrict__ A, const u16* __restrict__ Bt,
    const float* __restrict__ bias, u16* __restrict__ outb, float* __restrict__ outf,
    const float* __restrict__ resf, int M, int N, int K, int epi) {
  __shared__ __attribute__((aligned(16))) u16 Ls[65536];  // 128 KB
  const int tid = threadIdx.x;
  const int wv = tid >> 6, lane = tid & 63;
  const int l15 = lane & 15, quad = lane >> 4;
  const int wm = wv >> 2, wn = wv & 3;
  const int m0 = blockIdx.x * 256, n0 = blockIdx.y * 256;

  // staging source (pre-swizzled): thread t -> row tid>>2, slot_raw=((t&3)-(t>>3))&3
  const int srow = tid >> 2;
  const int scol = (((tid & 3) - (tid >> 3)) & 3) * 8;
  const u16* pA = A + (size_t)(m0 + srow) * K + scol;
  const u16* pB = Bt + (size_t)(n0 + srow) * K + scol;
  const int dst = tid * 8;  // u16 offset inside an 8KB chunk

  // bias first so in-loop vmcnt counts stay exact
  float bvv[4];
#pragma unroll
  for (int nt = 0; nt < 4; nt++) bvv[nt] = bias[n0 + wn * 64 + nt * 16 + l15];

#define STAGE_A(tt, half)                                              \
  do {                                                                 \
    const u16* s_ = pA + (size_t)(tt)*64 + (size_t)(half)*128 * K;     \
    u16* d_ = Ls + ((tt)&1) * 32768 + (half)*4096 + dst;               \
    gld16(s_, d_);                                                     \
    gld16(s_ + 32, d_ + 8192);                                         \
  } while (0)
#define STAGE_B(tt, half)                                              \
  do {                                                                 \
    const u16* s_ = pB + (size_t)(tt)*64 + (size_t)(half)*128 * K;     \
    u16* d_ = Ls + ((tt)&1) * 32768 + 16384 + (half)*4096 + dst;       \
    gld16(s_, d_);                                                     \
    gld16(s_ + 32, d_ + 8192);                                         \
  } while (0)

  f32x4 zero4 = {0.f, 0.f, 0.f, 0.f};
  f32x4 acc[8][4];
#pragma unroll
  for (int i = 0; i < 8; i++)
#pragma unroll
    for (int j = 0; j < 4; j++) acc[i][j] = zero4;

  const int kiter = K >> 6;  // always >= 8 here

  // prologue: tile0 fully, tile1 {A0,B0,A1}; vmcnt(6) -> tile0 resident
  STAGE_A(0, 0); STAGE_B(0, 0); STAGE_A(0, 1); STAGE_B(0, 1);
  asm volatile("" ::: "memory");
  STAGE_A(1, 0); STAGE_B(1, 0); STAGE_A(1, 1);
  asm volatile("s_waitcnt vmcnt(6)" ::: "memory");
  __builtin_amdgcn_s_barrier();
  asm volatile("" ::: "memory");

  short8 aF[4][2], b0f[2][2], b1f[2][2];
  for (int t = 0; t < kiter; ++t) {
    const int buf = t & 1;
    const u16* Ab = Ls + buf * 32768;
    const u16* Bb = Ab + 16384;
    // ------- window 1: quadrants (0,0)+(0,1); stage B1(t+1) -------
    if (t + 1 < kiter) STAGE_B(t + 1, 1);
#pragma unroll
    for (int fm = 0; fm < 4; fm++)
#pragma unroll
      for (int s = 0; s < 2; s++) {
        int row = wm * 128 + fm * 16 + l15;
        aF[fm][s] = ld8(Ab + s * 8192 + row * 32 + ((quad + (row >> 1)) & 3) * 8);
      }
#pragma unroll
    for (int fn = 0; fn < 2; fn++)
#pragma unroll
      for (int s = 0; s < 2; s++) {
        int row = wn * 64 + fn * 16 + l15;
        b0f[fn][s] = ld8(Bb + s * 8192 + row * 32 + ((quad + (row >> 1)) & 3) * 8);
      }
#pragma unroll
    for (int fn = 0; fn < 2; fn++)
#pragma unroll
      for (int s = 0; s < 2; s++) {
        int row = wn * 64 + 32 + fn * 16 + l15;
        b1f[fn][s] = ld8(Bb + s * 8192 + row * 32 + ((quad + (row >> 1)) & 3) * 8);
      }
    __builtin_amdgcn_s_setprio(1);
#pragma unroll
    for (int fm = 0; fm < 4; fm++)
#pragma unroll
      for (int fn = 0; fn < 2; fn++) {
        acc[fm][fn] = __builtin_amdgcn_mfma_f32_16x16x32_bf16(aF[fm][0], b0f[fn][0], acc[fm][fn], 0, 0, 0);
        acc[fm][fn] = __builtin_amdgcn_mfma_f32_16x16x32_bf16(aF[fm][1], b0f[fn][1], acc[fm][fn], 0, 0, 0);
      }
#pragma unroll
    for (int fm = 0; fm < 4; fm++)
#pragma unroll
      for (int fn = 0; fn < 2; fn++) {
        acc[fm][2 + fn] = __builtin_amdgcn_mfma_f32_16x16x32_bf16(aF[fm][0], b1f[fn][0], acc[fm][2 + fn], 0, 0, 0);
        acc[fm][2 + fn] = __builtin_amdgcn_mfma_f32_16x16x32_bf16(aF[fm][1], b1f[fn][1], acc[fm][2 + fn], 0, 0, 0);
      }
    __builtin_amdgcn_s_setprio(0);
    barx();
    // ------- window 2: quadrant (1,1); stage B0(t+2) -------
    if (t + 2 < kiter) STAGE_B(t + 2, 0);
#pragma unroll
    for (int fm = 0; fm < 4; fm++)
#pragma unroll
      for (int s = 0; s < 2; s++) {
        int row = wm * 128 + 64 + fm * 16 + l15;
        aF[fm][s] = ld8(Ab + s * 8192 + row * 32 + ((quad + (row >> 1)) & 3) * 8);
      }
    __builtin_amdgcn_s_setprio(1);
#pragma unroll
    for (int fm = 0; fm < 4; fm++)
#pragma unroll
      for (int fn = 0; fn < 2; fn++) {
        acc[4 + fm][2 + fn] = __builtin_amdgcn_mfma_f32_16x16x32_bf16(aF[fm][0], b1f[fn][0], acc[4 + fm][2 + fn], 0, 0, 0);
        acc[4 + fm][2 + fn] = __builtin_amdgcn_mfma_f32_16x16x32_bf16(aF[fm][1], b1f[fn][1], acc[4 + fm][2 + fn], 0, 0, 0);
      }
    __builtin_amdgcn_s_setprio(0);
    barx();
    // ------- window 3: quadrant (1,0); stage A0(t+2)+A1(t+2) -------
    if (t + 2 < kiter) {
      STAGE_A(t + 2, 0);
      STAGE_A(t + 2, 1);
    }
    __builtin_amdgcn_s_setprio(1);
#pragma unroll
    for (int fm = 0; fm < 4; fm++)
#pragma unroll
      for (int fn = 0; fn < 2; fn++) {
        acc[4 + fm][fn] = __builtin_amdgcn_mfma_f32_16x16x32_bf16(aF[fm][0], b0f[fn][0], acc[4 + fm][fn], 0, 0, 0);
        acc[4 + fm][fn] = __builtin_amdgcn_mfma_f32_16x16x32_bf16(aF[fm][1], b0f[fn][1], acc[4 + fm][fn], 0, 0, 0);
      }
    __builtin_amdgcn_s_setprio(0);
    if (t + 1 < kiter) {
      if (t + 2 < kiter) {
        asm volatile("s_waitcnt vmcnt(6)" ::: "memory");
      } else {
        asm volatile("s_waitcnt vmcnt(0)" ::: "memory");
      }
      __builtin_amdgcn_s_barrier();
      asm volatile("" ::: "memory");
    }
  }
#undef STAGE_A
#undef STAGE_B

  // epilogue: per-wave 128x64 at (m0+wm*128, n0+wn*64); acc[i][j] -> +i*16/+j*16
#pragma unroll
  for (int mt = 0; mt < 8; mt++) {
#pragma unroll
    for (int rr = 0; rr < 4; rr++) {
      int gm = m0 + wm * 128 + mt * 16 + quad * 4 + rr;
      size_t rowbase = 0;
      if (epi == 1) {
        int tok = gm & 63, winin = (gm >> 6) & 63, bb = gm >> 12;
        int sr = (winin >> 3) * 8 + (tok >> 3);
        int sc = (winin & 7) * 8 + (tok & 7);
        int fr = (sr + SHIFT_) & 63, fc = (sc + SHIFT_) & 63;
        rowbase = ((size_t)bb * 4096 + fr * 64 + fc) * 512;
      } else if (epi == 3) {
        rowbase = (size_t)gm * 512;
      } else if (epi == 2) {
        rowbase = (size_t)gm * N;
      }
#pragma unroll
      for (int nt = 0; nt < 4; nt++) {
        int gn = n0 + wn * 64 + nt * 16 + l15;
        float val = acc[mt][nt][rr] + bvv[nt];
        if (epi == 0) {
          int part = gn >> 9, hh = (gn >> 5) & 15, dd = gn & 31;
          size_t dstg = (((size_t)(part * 16 + hh) * 32768) + gm) * 32 + dd;
          outb[dstg] = f2bf(val);
        } else if (epi == 2) {
          outb[rowbase + gn] = f2bf(gelu_t(val));
        } else {
          size_t idx = rowbase + gn;
          outf[idx] = resf[idx] + val;
        }
      }
    }
  }
}

// ---------------- attention: one wave per (window, head) ----------------
// q/k/v: head-major [h][32768][32] bf16 (contiguous 64x32 tile per win,h)
__global__ __launch_bounds__(64) void attn(const u16* __restrict__ q, const u16* __restrict__ k,
                                           const u16* __restrict__ v, const float* __restrict__ tbl,
                                           u16* __restrict__ ctx) {
  __shared__ __attribute__((aligned(16))) u16 Pl[64 * 80];
  __shared__ __attribute__((aligned(16))) u16 Vt[32 * 72];  // V^T: [dim][token]
  __shared__ float tb[225];
  const int win = blockIdx.x, h = blockIdx.y;
  const int lane = threadIdx.x;
  const int l15 = lane & 15, quad = lane >> 4;

  for (int idx = lane; idx < 225; idx += 64) tb[idx] = tbl[idx * 16 + h];

  const size_t tilebase = ((size_t)h * 32768 + win * 64) * 32;
  const u16* qh = q + tilebase;
  const u16* kh = k + tilebase;
  const u16* vh = v + tilebase;

  // stage V transposed via fully-coalesced b128 loads
#pragma unroll
  for (int rnd = 0; rnd < 4; rnd++) {
    int t = rnd * 16 + (lane >> 2);
    int c = (lane & 3) * 8;
    short8 vrow = ld8(vh + t * 32 + c);
#pragma unroll
    for (int j = 0; j < 8; j++) Vt[(c + j) * 72 + t] = (u16)vrow[j];
  }

  short8 aq[4], bkf[4];
#pragma unroll
  for (int mt = 0; mt < 4; mt++) aq[mt] = ld8(qh + (mt * 16 + l15) * 32 + quad * 8);
#pragma unroll
  for (int nt = 0; nt < 4; nt++) bkf[nt] = ld8(kh + (nt * 16 + l15) * 32 + quad * 8);

  f32x4 zero4 = {0.f, 0.f, 0.f, 0.f};
  f32x4 s[4][4];
#pragma unroll
  for (int i = 0; i < 4; i++)
#pragma unroll
    for (int j = 0; j < 4; j++) s[i][j] = zero4;
#pragma unroll
  for (int mt = 0; mt < 4; mt++)
#pragma unroll
    for (int nt = 0; nt < 4; nt++)
      s[mt][nt] = __builtin_amdgcn_mfma_f32_16x16x32_bf16(aq[mt], bkf[nt], s[mt][nt], 0, 0, 0);

  __syncthreads();  // tb + Vt ready

  const int winin = win & 63;
  const int wrow0 = (winin >> 3) * 8, wcol0 = (winin & 7) * 8;
  int valc[4], ci[4], cj[4];
#pragma unroll
  for (int nt = 0; nt < 4; nt++) {
    int ct = nt * 16 + l15;
    ci[nt] = ct >> 3;
    cj[nt] = ct & 7;
    int rr_ = wrow0 + ci[nt], cc_ = wcol0 + cj[nt];
    valc[nt] = 3 * (rr_ < 56 ? 0 : (rr_ < 60 ? 1 : 2)) + (cc_ < 56 ? 0 : (cc_ < 60 ? 1 : 2));
  }
  const float scale = 0.17677669529663687f;  // 1/sqrt(32)
#pragma unroll
  for (int mt = 0; mt < 4; mt++) {
#pragma unroll
    for (int rr = 0; rr < 4; rr++) {
      int rt = mt * 16 + quad * 4 + rr;
      int i1 = rt >> 3, j1 = rt & 7;
      int rrow = wrow0 + i1, rcol = wcol0 + j1;
      int valr = 3 * (rrow < 56 ? 0 : (rrow < 60 ? 1 : 2)) + (rcol < 56 ? 0 : (rcol < 60 ? 1 : 2));
      float sv[4];
      float sum = 0.f;
      // scores are O(+-10): exp without max-subtraction is safe in fp32
#pragma unroll
      for (int nt = 0; nt < 4; nt++) {
        int idx = (i1 - ci[nt] + 7) * 15 + (j1 - cj[nt] + 7);
        float e = s[mt][nt][rr] * scale + tb[idx] + (valr == valc[nt] ? 0.f : -100.f);
        sv[nt] = __expf(e);
        sum += sv[nt];
      }
#pragma unroll
      for (int m = 1; m < 16; m <<= 1) sum += __shfl_xor(sum, m);
      float inv = 1.f / sum;
#pragma unroll
      for (int nt = 0; nt < 4; nt++) Pl[rt * 80 + nt * 16 + l15] = f2bf(sv[nt] * inv);
    }
  }
  __syncthreads();

  // O = P(64x64) @ V(64x32), V^T from LDS
  f32x4 o[4][2];
#pragma unroll
  for (int i = 0; i < 4; i++)
#pragma unroll
    for (int j = 0; j < 2; j++) o[i][j] = zero4;
#pragma unroll
  for (int kk = 0; kk < 2; kk++) {
    short8 bv2[2];
#pragma unroll
    for (int nt = 0; nt < 2; nt++)
      bv2[nt] = ld8(Vt + (nt * 16 + l15) * 72 + kk * 32 + quad * 8);
#pragma unroll
    for (int mt = 0; mt < 4; mt++) {
      short8 ap = ld8(Pl + (mt * 16 + l15) * 80 + kk * 32 + quad * 8);
#pragma unroll
      for (int nt = 0; nt < 2; nt++)
        o[mt][nt] = __builtin_amdgcn_mfma_f32_16x16x32_bf16(ap, bv2[nt], o[mt][nt], 0, 0, 0);
    }
  }
  const size_t cbase = (size_t)win * 64 * 512 + h * 32;
#pragma unroll
  for (int mt = 0; mt < 4; mt++)
#pragma unroll
    for (int rr = 0; rr < 4; rr++) {
      int rt = mt * 16 + quad * 4 + rr;
#pragma unroll
      for (int nt = 0; nt < 2; nt++)
        ctx[cbase + (size_t)rt * 512 + nt * 16 + l15] = f2bf(o[mt][nt][rr]);
    }
}

extern "C" void kernel_launch(void* const* d_in, const int* in_sizes, int n_in,
                              void* d_out, int out_size, void* d_ws, size_t ws_size,
                              hipStream_t stream) {
  const float* hs   = (const float*)d_in[0];
  const float* ln1g = (const float*)d_in[1];
  const float* ln1b = (const float*)d_in[2];
  const float* wq   = (const float*)d_in[3];
  const float* bq   = (const float*)d_in[4];
  const float* wk   = (const float*)d_in[5];
  const float* bk   = (const float*)d_in[6];
  const float* wvp  = (const float*)d_in[7];
  const float* bv   = (const float*)d_in[8];
  const float* tbl  = (const float*)d_in[9];
  const float* wo   = (const float*)d_in[10];
  const float* bo   = (const float*)d_in[11];
  const float* ln2g = (const float*)d_in[12];
  const float* ln2b = (const float*)d_in[13];
  const float* w1   = (const float*)d_in[14];
  const float* b1   = (const float*)d_in[15];
  const float* w2   = (const float*)d_in[16];
  const float* b2   = (const float*)d_in[17];
  float* out = (float*)d_out;
  u16* ws = (u16*)d_ws;

  const size_t S = (size_t)32768 * 512;
  u16* xw   = ws;          // LN1 out / ctx / LN2 out (bf16, S)
  u16* qb   = ws + S;      // Q head-major [16][32768][32]
  u16* kb   = ws + 2 * S;  // K head-major
  u16* vb   = ws + 3 * S;  // V head-major
  u16* y1   = ws + S;      // MLP intermediate (32768 x 2048 bf16, 4S) after attn
  u16* wt   = ws + 5 * S;  // transposed weights (bf16)
  u16* wqkvT = wt;         // 1536 x 512 (wq^T | wk^T | wv^T rows)
  u16* woT  = wt + 786432;
  u16* w1T  = wt + 1048576;
  u16* w2T  = wt + 2097152;
  float* bcat = (float*)(wt + 3145728);  // 1536 fp32
  float* hid = out;        // residual stream lives in d_out (fp32)

  transp<<<dim3(16, 16), 256, 0, stream>>>(wq, wqkvT, 512, 512);
  transp<<<dim3(16, 16), 256, 0, stream>>>(wk, wqkvT + 262144, 512, 512);
  transp<<<dim3(16, 16), 256, 0, stream>>>(wvp, wqkvT + 524288, 512, 512);
  transp<<<dim3(16, 16), 256, 0, stream>>>(wo, woT, 512, 512);
  transp<<<dim3(64, 16), 256, 0, stream>>>(w1, w1T, 512, 2048);
  transp<<<dim3(16, 64), 256, 0, stream>>>(w2, w2T, 2048, 512);
  concat_bias<<<6, 256, 0, stream>>>(bq, bk, bv, bcat);

  ln_win<<<8192, 256, 0, stream>>>(hs, ln1g, ln1b, xw, 1);

  // fused QKV: (32768 x 512) @ (512 x 1536) -> head-major Q/K/V at ws+S
  gemm_bt<<<dim3(128, 6), 512, 0, stream>>>(xw, wqkvT, bcat, qb, nullptr, nullptr,
                                            32768, 1536, 512, 0);

  attn<<<dim3(512, 16), 64, 0, stream>>>(qb, kb, vb, tbl, xw);

  // hid = hs + window_reverse(ctx @ Wo + bo)   (fp32, into d_out)
  gemm_bt<<<dim3(128, 2), 512, 0, stream>>>(xw, woT, bo, nullptr, hid, hs,
                                            32768, 512, 512, 1);

  // LN2(hid) -> xw (bf16)
  ln_win<<<8192, 256, 0, stream>>>(hid, ln2g, ln2b, xw, 0);

  // y1 = gelu(LN2 @ w1 + b1), full M
  gemm_bt<<<dim3(128, 8), 512, 0, stream>>>(xw, w1T, b1, y1, nullptr, nullptr,
                                            32768, 2048, 512, 2);
  // out = hid + y1 @ w2T + b2  (fp32, in-place RMW on d_out)
  gemm_bt<<<dim3(128, 2), 512, 0, stream>>>(y1, w2T, b2, nullptr, out, hid,
                                            32768, 512, 2048, 3);
}

// Round 5
// 595.181 us; speedup vs baseline: 1.0819x; 1.0819x over previous
//
#include <hip/hip_runtime.h>

typedef unsigned short u16;
typedef __attribute__((ext_vector_type(8))) short short8;
typedef __attribute__((ext_vector_type(4))) float f32x4;

#define SHIFT_ 4

__device__ __forceinline__ float bf2f(u16 u) {
  unsigned x = ((unsigned)u) << 16;
  return __builtin_bit_cast(float, x);
}
__device__ __forceinline__ u16 f2bf(float f) {
  unsigned u = __builtin_bit_cast(unsigned, f);
  u += 0x7fffu + ((u >> 16) & 1u);
  return (u16)(u >> 16);
}
__device__ __forceinline__ short8 ld8(const u16* p) {
  return *(const short8*)p;
}
__device__ __forceinline__ void gld16(const void* g, void* l) {
  __builtin_amdgcn_global_load_lds(
      (const __attribute__((address_space(1))) unsigned int*)g,
      (__attribute__((address_space(3))) unsigned int*)l, 16, 0, 0);
}
// lean tanh-gelu (exp + rcp form)
__device__ __forceinline__ float gelu_t(float x) {
  float x2 = x * x;
  float u = x * (0.7978845608028654f + 0.0356774081f * x2);
  float t = __expf(u + u);
  float th = 1.f - 2.f * __builtin_amdgcn_rcpf(t + 1.f);
  return 0.5f * x * (1.f + th);
}

// ---------------- transpose + fp32->bf16 convert (R x C fp32 -> C x R bf16) --
__global__ void transp(const float* __restrict__ in, u16* __restrict__ out, int R, int C) {
  __shared__ u16 t[32][33];
  int tx = threadIdx.x & 31, ty = threadIdx.x >> 5;
  int c0 = blockIdx.x * 32, r0 = blockIdx.y * 32;
#pragma unroll
  for (int i = 0; i < 4; i++)
    t[ty + i * 8][tx] = f2bf(in[(size_t)(r0 + ty + i * 8) * C + c0 + tx]);
  __syncthreads();
#pragma unroll
  for (int i = 0; i < 4; i++)
    out[(size_t)(c0 + ty + i * 8) * R + r0 + tx] = t[tx][ty + i * 8];
}

__global__ void concat_bias(const float* __restrict__ a, const float* __restrict__ b,
                            const float* __restrict__ c, float* __restrict__ o) {
  int i = blockIdx.x * 256 + threadIdx.x;
  if (i < 512) o[i] = a[i];
  else if (i < 1024) o[i] = b[i - 512];
  else if (i < 1536) o[i] = c[i - 1024];
}

// ---------------- LayerNorm fp32 -> bf16 (optionally fused shift+window) -----
__global__ void ln_win(const float* __restrict__ hid, const float* __restrict__ g,
                       const float* __restrict__ b, u16* __restrict__ out, int windowed) {
  int wv = threadIdx.x >> 6, lane = threadIdx.x & 63;
  int tokid = blockIdx.x * 4 + wv;
  size_t src;
  if (windowed) {
    int t = tokid & 63, w = tokid >> 6;
    int winin = w & 63, bb = w >> 6;
    int r = ((winin >> 3) * 8 + (t >> 3) + SHIFT_) & 63;
    int c = ((winin & 7) * 8 + (t & 7) + SHIFT_) & 63;
    src = ((size_t)bb * 4096 + r * 64 + c) * 512;
  } else {
    src = (size_t)tokid * 512;
  }
  f32x4 x0 = *(const f32x4*)(hid + src + lane * 8);
  f32x4 x1 = *(const f32x4*)(hid + src + lane * 8 + 4);
  float x[8];
#pragma unroll
  for (int e = 0; e < 4; e++) { x[e] = x0[e]; x[e + 4] = x1[e]; }
  float s = 0.f, s2 = 0.f;
#pragma unroll
  for (int e = 0; e < 8; e++) {
    s += x[e];
    s2 += x[e] * x[e];
  }
#pragma unroll
  for (int m = 1; m < 64; m <<= 1) {
    s += __shfl_xor(s, m);
    s2 += __shfl_xor(s2, m);
  }
  float mean = s * (1.f / 512.f);
  float var = s2 * (1.f / 512.f) - mean * mean;
  float rstd = rsqrtf(var + 1e-5f);
  u16 pack[8];
#pragma unroll
  for (int e = 0; e < 8; e++) {
    int c = lane * 8 + e;
    float y = (x[e] - mean) * rstd * g[c] + b[c];
    pack[e] = f2bf(y);
  }
  *(short8*)(out + (size_t)tokid * 512 + lane * 8) = *(const short8*)pack;
}

// ---------------- GEMM variant 1 (round-0 verbatim): 2-phase, 48KB LDS -----
// Tile 256x128, BK=32, 512 threads (8 waves, 64x64 each). Double-buffered LDS,
// one barrier per K-iter (full drain via __syncthreads). ~3 blocks/CU.
// Used for epi 0 (QKV) and epi 1 (Wo) — occupancy-sensitive dispatches.
__global__ __launch_bounds__(512) void gemm_db(
    const u16* __restrict__ A, const u16* __restrict__ Bt,
    const float* __restrict__ bias, u16* __restrict__ outb, float* __restrict__ outf,
    const float* __restrict__ resf, int M, int N, int K, int epi) {
  constexpr int BUF = (256 + 128) * 32;  // u16 per buffer (A 8192 + B 4096)
  __shared__ __attribute__((aligned(16))) u16 Ls[2 * BUF];
  const int tid = threadIdx.x;
  const int wv = tid >> 6, lane = tid & 63;
  const int l15 = lane & 15, quad = lane >> 4;
  const int m0 = blockIdx.x * 256, n0 = blockIdx.y * 128;
  const int wm = (wv >> 1) * 64, wn = (wv & 1) * 64;

  const int arow = tid >> 2;  // 0..127
  const int acol = (((tid & 3) - (tid >> 3)) & 3) * 8;
  const u16* gA = A + (size_t)(m0 + arow) * K + acol;
  const u16* gB = Bt + (size_t)(n0 + arow) * K + acol;
  const int lAoff = tid * 8;
  const int lA2off = 4096 + tid * 8;
  const int lBoff = 8192 + tid * 8;

  f32x4 zero4 = {0.f, 0.f, 0.f, 0.f};
  f32x4 acc[4][4];
#pragma unroll
  for (int i = 0; i < 4; i++)
#pragma unroll
    for (int j = 0; j < 4; j++) acc[i][j] = zero4;

  const int kiter = K >> 5;
  {
    u16* base = Ls;
    gld16(gA, base + lAoff);
    gld16(gA + (size_t)128 * K, base + lA2off);
    gld16(gB, base + lBoff);
  }
  int p = 0;
  for (int ko = 0; ko < kiter; ++ko) {
    __syncthreads();  // tile ko resident in buffer p
    if (ko + 1 < kiter) {
      u16* base = Ls + (p ^ 1) * BUF;
      const u16* a = gA + (ko + 1) * 32;
      gld16(a, base + lAoff);
      gld16(a + (size_t)128 * K, base + lA2off);
      gld16(gB + (ko + 1) * 32, base + lBoff);
    }
    const u16* Ab = Ls + p * BUF;
    const u16* Bb = Ab + 8192;
    short8 af[4], bfr[4];
#pragma unroll
    for (int mt = 0; mt < 4; mt++) {
      int row = wm + mt * 16 + l15;
      af[mt] = ld8(Ab + (row * 4 + ((quad + (row >> 1)) & 3)) * 8);
    }
#pragma unroll
    for (int nt = 0; nt < 4; nt++) {
      int row = wn + nt * 16 + l15;
      bfr[nt] = ld8(Bb + (row * 4 + ((quad + (row >> 1)) & 3)) * 8);
    }
#pragma unroll
    for (int mt = 0; mt < 4; mt++)
#pragma unroll
      for (int nt = 0; nt < 4; nt++)
        acc[mt][nt] = __builtin_amdgcn_mfma_f32_16x16x32_bf16(af[mt], bfr[nt], acc[mt][nt], 0, 0, 0);
    p ^= 1;
  }

  float bvv[4];
#pragma unroll
  for (int nt = 0; nt < 4; nt++) bvv[nt] = bias[n0 + wn + nt * 16 + l15];

#pragma unroll
  for (int mt = 0; mt < 4; mt++) {
#pragma unroll
    for (int rr = 0; rr < 4; rr++) {
      int gm = m0 + wm + mt * 16 + quad * 4 + rr;
      size_t rowbase = 0;
      if (epi == 1) {
        int tok = gm & 63, winin = (gm >> 6) & 63, bb = gm >> 12;
        int sr = (winin >> 3) * 8 + (tok >> 3);
        int sc = (winin & 7) * 8 + (tok & 7);
        int fr = (sr + SHIFT_) & 63, fc = (sc + SHIFT_) & 63;
        rowbase = ((size_t)bb * 4096 + fr * 64 + fc) * 512;
      } else if (epi == 3) {
        rowbase = (size_t)gm * 512;
      } else if (epi == 2) {
        rowbase = (size_t)gm * N;
      }
#pragma unroll
      for (int nt = 0; nt < 4; nt++) {
        int gn = n0 + wn + nt * 16 + l15;
        float val = acc[mt][nt][rr] + bvv[nt];
        if (epi == 0) {
          int part = gn >> 9, hh = (gn >> 5) & 15, dd = gn & 31;
          size_t dst = (((size_t)(part * 16 + hh) * 32768) + gm) * 32 + dd;
          outb[dst] = f2bf(val);
        } else if (epi == 2) {
          outb[rowbase + gn] = f2bf(gelu_t(val));
        } else {
          size_t idx = rowbase + gn;
          outf[idx] = resf[idx] + val;
        }
      }
    }
  }
}

// ---------------- GEMM variant 2 (round-1 verbatim): tri-buffer, 72KB ------
// Tile 256x128, BK=32, 512 threads. TRIPLE-buffered LDS, prefetch depth 2,
// counted vmcnt gates (vmcnt(3) steady state), raw s_barrier, setprio around
// MFMA. 2 blocks/CU. Used for epi 2 (MLP1) and epi 3 (MLP2) — proven
// 143.6 -> 128.0 and ~140 -> 128.2 on these dispatches (round-1 rocprof).
__global__ __launch_bounds__(512) void gemm_tb(
    const u16* __restrict__ A, const u16* __restrict__ Bt,
    const float* __restrict__ bias, u16* __restrict__ outb, float* __restrict__ outf,
    const float* __restrict__ resf, int M, int N, int K, int epi) {
  constexpr int BUF = (256 + 128) * 32;
  __shared__ __attribute__((aligned(16))) u16 Ls[3 * BUF];
  const int tid = threadIdx.x;
  const int wv = tid >> 6, lane = tid & 63;
  const int l15 = lane & 15, quad = lane >> 4;
  const int m0 = blockIdx.x * 256, n0 = blockIdx.y * 128;
  const int wm = (wv >> 1) * 64, wn = (wv & 1) * 64;

  const int arow = tid >> 2;
  const int acol = (((tid & 3) - (tid >> 3)) & 3) * 8;
  const u16* gA = A + (size_t)(m0 + arow) * K + acol;
  const u16* gB = Bt + (size_t)(n0 + arow) * K + acol;
  const int lAoff = tid * 8;
  const int lA2off = 4096 + tid * 8;
  const int lBoff = 8192 + tid * 8;

  f32x4 zero4 = {0.f, 0.f, 0.f, 0.f};
  f32x4 acc[4][4];
#pragma unroll
  for (int i = 0; i < 4; i++)
#pragma unroll
    for (int j = 0; j < 4; j++) acc[i][j] = zero4;

  const int kiter = K >> 5;
  // prologue: stage tiles 0 and 1 into buffers 0 and 1
  {
    gld16(gA, Ls + lAoff);
    gld16(gA + (size_t)128 * K, Ls + lA2off);
    gld16(gB, Ls + lBoff);
    u16* base = Ls + BUF;
    const u16* a = gA + 32;
    gld16(a, base + lAoff);
    gld16(a + (size_t)128 * K, base + lA2off);
    gld16(gB + 32, base + lBoff);
  }
  int ci = 0;
  for (int ko = 0; ko < kiter; ++ko) {
    if (ko + 1 < kiter) {
      asm volatile("s_waitcnt vmcnt(3)" ::: "memory");
    } else {
      asm volatile("s_waitcnt vmcnt(0)" ::: "memory");
    }
    __builtin_amdgcn_s_barrier();
    asm volatile("" ::: "memory");
    if (ko + 2 < kiter) {
      int si = ci + 2;
      if (si >= 3) si -= 3;
      u16* base = Ls + si * BUF;
      const u16* a = gA + (size_t)(ko + 2) * 32;
      gld16(a, base + lAoff);
      gld16(a + (size_t)128 * K, base + lA2off);
      gld16(gB + (size_t)(ko + 2) * 32, base + lBoff);
    }
    const u16* Ab = Ls + ci * BUF;
    const u16* Bb = Ab + 8192;
    short8 af[4], bfr[4];
#pragma unroll
    for (int mt = 0; mt < 4; mt++) {
      int row = wm + mt * 16 + l15;
      af[mt] = ld8(Ab + (row * 4 + ((quad + (row >> 1)) & 3)) * 8);
    }
#pragma unroll
    for (int nt = 0; nt < 4; nt++) {
      int row = wn + nt * 16 + l15;
      bfr[nt] = ld8(Bb + (row * 4 + ((quad + (row >> 1)) & 3)) * 8);
    }
    __builtin_amdgcn_s_setprio(1);
#pragma unroll
    for (int mt = 0; mt < 4; mt++)
#pragma unroll
      for (int nt = 0; nt < 4; nt++)
        acc[mt][nt] = __builtin_amdgcn_mfma_f32_16x16x32_bf16(af[mt], bfr[nt], acc[mt][nt], 0, 0, 0);
    __builtin_amdgcn_s_setprio(0);
    ci = (ci == 2) ? 0 : ci + 1;
  }

  float bvv[4];
#pragma unroll
  for (int nt = 0; nt < 4; nt++) bvv[nt] = bias[n0 + wn + nt * 16 + l15];

#pragma unroll
  for (int mt = 0; mt < 4; mt++) {
#pragma unroll
    for (int rr = 0; rr < 4; rr++) {
      int gm = m0 + wm + mt * 16 + quad * 4 + rr;
      size_t rowbase = 0;
      if (epi == 1) {
        int tok = gm & 63, winin = (gm >> 6) & 63, bb = gm >> 12;
        int sr = (winin >> 3) * 8 + (tok >> 3);
        int sc = (winin & 7) * 8 + (tok & 7);
        int fr = (sr + SHIFT_) & 63, fc = (sc + SHIFT_) & 63;
        rowbase = ((size_t)bb * 4096 + fr * 64 + fc) * 512;
      } else if (epi == 3) {
        rowbase = (size_t)gm * 512;
      } else if (epi == 2) {
        rowbase = (size_t)gm * N;
      }
#pragma unroll
      for (int nt = 0; nt < 4; nt++) {
        int gn = n0 + wn + nt * 16 + l15;
        float val = acc[mt][nt][rr] + bvv[nt];
        if (epi == 0) {
          int part = gn >> 9, hh = (gn >> 5) & 15, dd = gn & 31;
          size_t dst = (((size_t)(part * 16 + hh) * 32768) + gm) * 32 + dd;
          outb[dst] = f2bf(val);
        } else if (epi == 2) {
          outb[rowbase + gn] = f2bf(gelu_t(val));
        } else {
          size_t idx = rowbase + gn;
          outf[idx] = resf[idx] + val;
        }
      }
    }
  }
}

// ---------------- attention: one wave per (window, head) ----------------
// q/k/v: head-major [h][32768][32] bf16 (contiguous 64x32 tile per win,h)
__global__ __launch_bounds__(64) void attn(const u16* __restrict__ q, const u16* __restrict__ k,
                                           const u16* __restrict__ v, const float* __restrict__ tbl,
                                           u16* __restrict__ ctx) {
  __shared__ __attribute__((aligned(16))) u16 Pl[64 * 80];
  __shared__ __attribute__((aligned(16))) u16 Vt[32 * 72];  // V^T: [dim][token]
  __shared__ float tb[225];
  const int win = blockIdx.x, h = blockIdx.y;
  const int lane = threadIdx.x;
  const int l15 = lane & 15, quad = lane >> 4;

  for (int idx = lane; idx < 225; idx += 64) tb[idx] = tbl[idx * 16 + h];

  const size_t tilebase = ((size_t)h * 32768 + win * 64) * 32;
  const u16* qh = q + tilebase;
  const u16* kh = k + tilebase;
  const u16* vh = v + tilebase;

  // stage V transposed via fully-coalesced b128 loads
#pragma unroll
  for (int rnd = 0; rnd < 4; rnd++) {
    int t = rnd * 16 + (lane >> 2);
    int c = (lane & 3) * 8;
    short8 vrow = ld8(vh + t * 32 + c);
#pragma unroll
    for (int j = 0; j < 8; j++) Vt[(c + j) * 72 + t] = (u16)vrow[j];
  }

  short8 aq[4], bkf[4];
#pragma unroll
  for (int mt = 0; mt < 4; mt++) aq[mt] = ld8(qh + (mt * 16 + l15) * 32 + quad * 8);
#pragma unroll
  for (int nt = 0; nt < 4; nt++) bkf[nt] = ld8(kh + (nt * 16 + l15) * 32 + quad * 8);

  f32x4 zero4 = {0.f, 0.f, 0.f, 0.f};
  f32x4 s[4][4];
#pragma unroll
  for (int i = 0; i < 4; i++)
#pragma unroll
    for (int j = 0; j < 4; j++) s[i][j] = zero4;
#pragma unroll
  for (int mt = 0; mt < 4; mt++)
#pragma unroll
    for (int nt = 0; nt < 4; nt++)
      s[mt][nt] = __builtin_amdgcn_mfma_f32_16x16x32_bf16(aq[mt], bkf[nt], s[mt][nt], 0, 0, 0);

  __syncthreads();  // tb + Vt ready

  const int winin = win & 63;
  const int wrow0 = (winin >> 3) * 8, wcol0 = (winin & 7) * 8;
  int valc[4], ci[4], cj[4];
#pragma unroll
  for (int nt = 0; nt < 4; nt++) {
    int ct = nt * 16 + l15;
    ci[nt] = ct >> 3;
    cj[nt] = ct & 7;
    int rr_ = wrow0 + ci[nt], cc_ = wcol0 + cj[nt];
    valc[nt] = 3 * (rr_ < 56 ? 0 : (rr_ < 60 ? 1 : 2)) + (cc_ < 56 ? 0 : (cc_ < 60 ? 1 : 2));
  }
  const float scale = 0.17677669529663687f;  // 1/sqrt(32)
#pragma unroll
  for (int mt = 0; mt < 4; mt++) {
#pragma unroll
    for (int rr = 0; rr < 4; rr++) {
      int rt = mt * 16 + quad * 4 + rr;
      int i1 = rt >> 3, j1 = rt & 7;
      int rrow = wrow0 + i1, rcol = wcol0 + j1;
      int valr = 3 * (rrow < 56 ? 0 : (rrow < 60 ? 1 : 2)) + (rcol < 56 ? 0 : (rcol < 60 ? 1 : 2));
      float sv[4];
      float sum = 0.f;
      // scores are O(+-10): exp without max-subtraction is safe in fp32
#pragma unroll
      for (int nt = 0; nt < 4; nt++) {
        int idx = (i1 - ci[nt] + 7) * 15 + (j1 - cj[nt] + 7);
        float e = s[mt][nt][rr] * scale + tb[idx] + (valr == valc[nt] ? 0.f : -100.f);
        sv[nt] = __expf(e);
        sum += sv[nt];
      }
#pragma unroll
      for (int m = 1; m < 16; m <<= 1) sum += __shfl_xor(sum, m);
      float inv = 1.f / sum;
#pragma unroll
      for (int nt = 0; nt < 4; nt++) Pl[rt * 80 + nt * 16 + l15] = f2bf(sv[nt] * inv);
    }
  }
  __syncthreads();

  // O = P(64x64) @ V(64x32), V^T from LDS
  f32x4 o[4][2];
#pragma unroll
  for (int i = 0; i < 4; i++)
#pragma unroll
    for (int j = 0; j < 2; j++) o[i][j] = zero4;
#pragma unroll
  for (int kk = 0; kk < 2; kk++) {
    short8 bv2[2];
#pragma unroll
    for (int nt = 0; nt < 2; nt++)
      bv2[nt] = ld8(Vt + (nt * 16 + l15) * 72 + kk * 32 + quad * 8);
#pragma unroll
    for (int mt = 0; mt < 4; mt++) {
      short8 ap = ld8(Pl + (mt * 16 + l15) * 80 + kk * 32 + quad * 8);
#pragma unroll
      for (int nt = 0; nt < 2; nt++)
        o[mt][nt] = __builtin_amdgcn_mfma_f32_16x16x32_bf16(ap, bv2[nt], o[mt][nt], 0, 0, 0);
    }
  }
  const size_t cbase = (size_t)win * 64 * 512 + h * 32;
#pragma unroll
  for (int mt = 0; mt < 4; mt++)
#pragma unroll
    for (int rr = 0; rr < 4; rr++) {
      int rt = mt * 16 + quad * 4 + rr;
#pragma unroll
      for (int nt = 0; nt < 2; nt++)
        ctx[cbase + (size_t)rt * 512 + nt * 16 + l15] = f2bf(o[mt][nt][rr]);
    }
}

extern "C" void kernel_launch(void* const* d_in, const int* in_sizes, int n_in,
                              void* d_out, int out_size, void* d_ws, size_t ws_size,
                              hipStream_t stream) {
  const float* hs   = (const float*)d_in[0];
  const float* ln1g = (const float*)d_in[1];
  const float* ln1b = (const float*)d_in[2];
  const float* wq   = (const float*)d_in[3];
  const float* bq   = (const float*)d_in[4];
  const float* wk   = (const float*)d_in[5];
  const float* bk   = (const float*)d_in[6];
  const float* wvp  = (const float*)d_in[7];
  const float* bv   = (const float*)d_in[8];
  const float* tbl  = (const float*)d_in[9];
  const float* wo   = (const float*)d_in[10];
  const float* bo   = (const float*)d_in[11];
  const float* ln2g = (const float*)d_in[12];
  const float* ln2b = (const float*)d_in[13];
  const float* w1   = (const float*)d_in[14];
  const float* b1   = (const float*)d_in[15];
  const float* w2   = (const float*)d_in[16];
  const float* b2   = (const float*)d_in[17];
  float* out = (float*)d_out;
  u16* ws = (u16*)d_ws;

  const size_t S = (size_t)32768 * 512;
  u16* xw   = ws;          // LN1 out / ctx / LN2 out (bf16, S)
  u16* qb   = ws + S;      // Q head-major [16][32768][32]
  u16* kb   = ws + 2 * S;  // K head-major
  u16* vb   = ws + 3 * S;  // V head-major
  u16* y1   = ws + S;      // MLP intermediate (32768 x 2048 bf16, 4S) after attn
  u16* wt   = ws + 5 * S;  // transposed weights (bf16)
  u16* wqkvT = wt;         // 1536 x 512 (wq^T | wk^T | wv^T rows)
  u16* woT  = wt + 786432;
  u16* w1T  = wt + 1048576;
  u16* w2T  = wt + 2097152;
  float* bcat = (float*)(wt + 3145728);  // 1536 fp32
  float* hid = out;        // residual stream lives in d_out (fp32)

  transp<<<dim3(16, 16), 256, 0, stream>>>(wq, wqkvT, 512, 512);
  transp<<<dim3(16, 16), 256, 0, stream>>>(wk, wqkvT + 262144, 512, 512);
  transp<<<dim3(16, 16), 256, 0, stream>>>(wvp, wqkvT + 524288, 512, 512);
  transp<<<dim3(16, 16), 256, 0, stream>>>(wo, woT, 512, 512);
  transp<<<dim3(64, 16), 256, 0, stream>>>(w1, w1T, 512, 2048);
  transp<<<dim3(16, 64), 256, 0, stream>>>(w2, w2T, 2048, 512);
  concat_bias<<<6, 256, 0, stream>>>(bq, bk, bv, bcat);

  ln_win<<<8192, 256, 0, stream>>>(hs, ln1g, ln1b, xw, 1);

  // fused QKV: (32768 x 512) @ (512 x 1536) -> head-major Q/K/V at ws+S
  gemm_db<<<dim3(128, 12), 512, 0, stream>>>(xw, wqkvT, bcat, qb, nullptr, nullptr,
                                             32768, 1536, 512, 0);

  attn<<<dim3(512, 16), 64, 0, stream>>>(qb, kb, vb, tbl, xw);

  // hid = hs + window_reverse(ctx @ Wo + bo)   (fp32, into d_out)
  gemm_db<<<dim3(128, 4), 512, 0, stream>>>(xw, woT, bo, nullptr, hid, hs,
                                            32768, 512, 512, 1);

  // LN2(hid) -> xw (bf16)
  ln_win<<<8192, 256, 0, stream>>>(hid, ln2g, ln2b, xw, 0);

  // y1 = gelu(LN2 @ w1 + b1), full M
  gemm_tb<<<dim3(128, 16), 512, 0, stream>>>(xw, w1T, b1, y1, nullptr, nullptr,
                                             32768, 2048, 512, 2);
  // out = hid + y1 @ w2T + b2  (fp32, in-place RMW on d_out)
  gemm_tb<<<dim3(128, 4), 512, 0, stream>>>(y1, w2T, b2, nullptr, out, hid,
                                            32768, 512, 2048, 3);
}

// Round 6
// 577.014 us; speedup vs baseline: 1.1160x; 1.0315x over previous
//
#include <hip/hip_runtime.h>

typedef unsigned short u16;
typedef __attribute__((ext_vector_type(8))) short short8;
typedef __attribute__((ext_vector_type(4))) float f32x4;

#define SHIFT_ 4

__device__ __forceinline__ float bf2f(u16 u) {
  unsigned x = ((unsigned)u) << 16;
  return __builtin_bit_cast(float, x);
}
__device__ __forceinline__ u16 f2bf(float f) {
  unsigned u = __builtin_bit_cast(unsigned, f);
  u += 0x7fffu + ((u >> 16) & 1u);
  return (u16)(u >> 16);
}
__device__ __forceinline__ short8 ld8(const u16* p) {
  return *(const short8*)p;
}
__device__ __forceinline__ void gld16(const void* g, void* l) {
  __builtin_amdgcn_global_load_lds(
      (const __attribute__((address_space(1))) unsigned int*)g,
      (__attribute__((address_space(3))) unsigned int*)l, 16, 0, 0);
}
// lean tanh-gelu (exp + rcp form)
__device__ __forceinline__ float gelu_t(float x) {
  float x2 = x * x;
  float u = x * (0.7978845608028654f + 0.0356774081f * x2);
  float t = __expf(u + u);
  float th = 1.f - 2.f * __builtin_amdgcn_rcpf(t + 1.f);
  return 0.5f * x * (1.f + th);
}

// ------ fused 4x transpose + fp32->bf16 (each 512x512), z selects matrix ----
__global__ void transp4(const float* __restrict__ i0, const float* __restrict__ i1,
                        const float* __restrict__ i2, const float* __restrict__ i3,
                        u16* __restrict__ o0, u16* __restrict__ o1,
                        u16* __restrict__ o2, u16* __restrict__ o3) {
  __shared__ u16 t[32][33];
  const float* in;
  u16* out;
  switch (blockIdx.z) {
    case 0: in = i0; out = o0; break;
    case 1: in = i1; out = o1; break;
    case 2: in = i2; out = o2; break;
    default: in = i3; out = o3; break;
  }
  int tx = threadIdx.x & 31, ty = threadIdx.x >> 5;
  int c0 = blockIdx.x * 32, r0 = blockIdx.y * 32;
#pragma unroll
  for (int i = 0; i < 4; i++)
    t[ty + i * 8][tx] = f2bf(in[(size_t)(r0 + ty + i * 8) * 512 + c0 + tx]);
  __syncthreads();
#pragma unroll
  for (int i = 0; i < 4; i++)
    out[(size_t)(c0 + ty + i * 8) * 512 + r0 + tx] = t[tx][ty + i * 8];
}

// ---------------- transpose + fp32->bf16 convert (R x C fp32 -> C x R bf16) --
__global__ void transp(const float* __restrict__ in, u16* __restrict__ out, int R, int C) {
  __shared__ u16 t[32][33];
  int tx = threadIdx.x & 31, ty = threadIdx.x >> 5;
  int c0 = blockIdx.x * 32, r0 = blockIdx.y * 32;
#pragma unroll
  for (int i = 0; i < 4; i++)
    t[ty + i * 8][tx] = f2bf(in[(size_t)(r0 + ty + i * 8) * C + c0 + tx]);
  __syncthreads();
#pragma unroll
  for (int i = 0; i < 4; i++)
    out[(size_t)(c0 + ty + i * 8) * R + r0 + tx] = t[tx][ty + i * 8];
}

__global__ void concat_bias(const float* __restrict__ a, const float* __restrict__ b,
                            const float* __restrict__ c, float* __restrict__ o) {
  int i = blockIdx.x * 256 + threadIdx.x;
  if (i < 512) o[i] = a[i];
  else if (i < 1024) o[i] = b[i - 512];
  else if (i < 1536) o[i] = c[i - 1024];
}

// ---------------- LayerNorm fp32 -> bf16 (optionally fused shift+window) -----
__global__ void ln_win(const float* __restrict__ hid, const float* __restrict__ g,
                       const float* __restrict__ b, u16* __restrict__ out, int windowed) {
  int wv = threadIdx.x >> 6, lane = threadIdx.x & 63;
  int tokid = blockIdx.x * 4 + wv;
  size_t src;
  if (windowed) {
    int t = tokid & 63, w = tokid >> 6;
    int winin = w & 63, bb = w >> 6;
    int r = ((winin >> 3) * 8 + (t >> 3) + SHIFT_) & 63;
    int c = ((winin & 7) * 8 + (t & 7) + SHIFT_) & 63;
    src = ((size_t)bb * 4096 + r * 64 + c) * 512;
  } else {
    src = (size_t)tokid * 512;
  }
  f32x4 x0 = *(const f32x4*)(hid + src + lane * 8);
  f32x4 x1 = *(const f32x4*)(hid + src + lane * 8 + 4);
  float x[8];
#pragma unroll
  for (int e = 0; e < 4; e++) { x[e] = x0[e]; x[e + 4] = x1[e]; }
  float s = 0.f, s2 = 0.f;
#pragma unroll
  for (int e = 0; e < 8; e++) {
    s += x[e];
    s2 += x[e] * x[e];
  }
#pragma unroll
  for (int m = 1; m < 64; m <<= 1) {
    s += __shfl_xor(s, m);
    s2 += __shfl_xor(s2, m);
  }
  float mean = s * (1.f / 512.f);
  float var = s2 * (1.f / 512.f) - mean * mean;
  float rstd = rsqrtf(var + 1e-5f);
  u16 pack[8];
#pragma unroll
  for (int e = 0; e < 8; e++) {
    int c = lane * 8 + e;
    float y = (x[e] - mean) * rstd * g[c] + b[c];
    pack[e] = f2bf(y);
  }
  *(short8*)(out + (size_t)tokid * 512 + lane * 8) = *(const short8*)pack;
}

// ---------------- GEMM (tri-buffer, counted vmcnt): C = A @ Bt^T + bias -----
// Tile 256x128, BK=32, 512 threads (8 waves, 64x64 each). TRIPLE-buffered LDS
// (72KB, 2 blocks/CU), prefetch depth 2, counted vmcnt(3) gates (vmcnt(0) only
// at the last step), raw s_barrier, setprio around the MFMA cluster. LDS slot
// swizzle (slot_raw + (row>>1)) & 3 -> ds_read_b128 2-way (free); staged via
// pre-swizzled global source + linear global_load_lds dest.
// Best measured per-dispatch of all session variants:
//   MLP1 128-134us, MLP2 128-135us, QKV <128us (r1/r5 rocprof).
// epi 0: head-major QKV  | epi 1: window-reverse+unshift + residual (fp32)
// epi 2: bf16(gelu(val)) | epi 3: outf = resf + val (fp32)
__global__ __launch_bounds__(512) void gemm_tb(
    const u16* __restrict__ A, const u16* __restrict__ Bt,
    const float* __restrict__ bias, u16* __restrict__ outb, float* __restrict__ outf,
    const float* __restrict__ resf, int M, int N, int K, int epi) {
  constexpr int BUF = (256 + 128) * 32;
  __shared__ __attribute__((aligned(16))) u16 Ls[3 * BUF];
  const int tid = threadIdx.x;
  const int wv = tid >> 6, lane = tid & 63;
  const int l15 = lane & 15, quad = lane >> 4;
  const int m0 = blockIdx.x * 256, n0 = blockIdx.y * 128;
  const int wm = (wv >> 1) * 64, wn = (wv & 1) * 64;

  const int arow = tid >> 2;
  const int acol = (((tid & 3) - (tid >> 3)) & 3) * 8;
  const u16* gA = A + (size_t)(m0 + arow) * K + acol;
  const u16* gB = Bt + (size_t)(n0 + arow) * K + acol;
  const int lAoff = tid * 8;
  const int lA2off = 4096 + tid * 8;
  const int lBoff = 8192 + tid * 8;

  f32x4 zero4 = {0.f, 0.f, 0.f, 0.f};
  f32x4 acc[4][4];
#pragma unroll
  for (int i = 0; i < 4; i++)
#pragma unroll
    for (int j = 0; j < 4; j++) acc[i][j] = zero4;

  const int kiter = K >> 5;
  // prologue: stage tiles 0 and 1 into buffers 0 and 1
  {
    gld16(gA, Ls + lAoff);
    gld16(gA + (size_t)128 * K, Ls + lA2off);
    gld16(gB, Ls + lBoff);
    u16* base = Ls + BUF;
    const u16* a = gA + 32;
    gld16(a, base + lAoff);
    gld16(a + (size_t)128 * K, base + lA2off);
    gld16(gB + 32, base + lBoff);
  }
  int ci = 0;
  for (int ko = 0; ko < kiter; ++ko) {
    if (ko + 1 < kiter) {
      asm volatile("s_waitcnt vmcnt(3)" ::: "memory");
    } else {
      asm volatile("s_waitcnt vmcnt(0)" ::: "memory");
    }
    __builtin_amdgcn_s_barrier();
    asm volatile("" ::: "memory");
    if (ko + 2 < kiter) {
      int si = ci + 2;
      if (si >= 3) si -= 3;
      u16* base = Ls + si * BUF;
      const u16* a = gA + (size_t)(ko + 2) * 32;
      gld16(a, base + lAoff);
      gld16(a + (size_t)128 * K, base + lA2off);
      gld16(gB + (size_t)(ko + 2) * 32, base + lBoff);
    }
    const u16* Ab = Ls + ci * BUF;
    const u16* Bb = Ab + 8192;
    short8 af[4], bfr[4];
#pragma unroll
    for (int mt = 0; mt < 4; mt++) {
      int row = wm + mt * 16 + l15;
      af[mt] = ld8(Ab + (row * 4 + ((quad + (row >> 1)) & 3)) * 8);
    }
#pragma unroll
    for (int nt = 0; nt < 4; nt++) {
      int row = wn + nt * 16 + l15;
      bfr[nt] = ld8(Bb + (row * 4 + ((quad + (row >> 1)) & 3)) * 8);
    }
    __builtin_amdgcn_s_setprio(1);
#pragma unroll
    for (int mt = 0; mt < 4; mt++)
#pragma unroll
      for (int nt = 0; nt < 4; nt++)
        acc[mt][nt] = __builtin_amdgcn_mfma_f32_16x16x32_bf16(af[mt], bfr[nt], acc[mt][nt], 0, 0, 0);
    __builtin_amdgcn_s_setprio(0);
    ci = (ci == 2) ? 0 : ci + 1;
  }

  float bvv[4];
#pragma unroll
  for (int nt = 0; nt < 4; nt++) bvv[nt] = bias[n0 + wn + nt * 16 + l15];

#pragma unroll
  for (int mt = 0; mt < 4; mt++) {
#pragma unroll
    for (int rr = 0; rr < 4; rr++) {
      int gm = m0 + wm + mt * 16 + quad * 4 + rr;
      size_t rowbase = 0;
      if (epi == 1) {
        int tok = gm & 63, winin = (gm >> 6) & 63, bb = gm >> 12;
        int sr = (winin >> 3) * 8 + (tok >> 3);
        int sc = (winin & 7) * 8 + (tok & 7);
        int fr = (sr + SHIFT_) & 63, fc = (sc + SHIFT_) & 63;
        rowbase = ((size_t)bb * 4096 + fr * 64 + fc) * 512;
      } else if (epi == 3) {
        rowbase = (size_t)gm * 512;
      } else if (epi == 2) {
        rowbase = (size_t)gm * N;
      }
#pragma unroll
      for (int nt = 0; nt < 4; nt++) {
        int gn = n0 + wn + nt * 16 + l15;
        float val = acc[mt][nt][rr] + bvv[nt];
        if (epi == 0) {
          int part = gn >> 9, hh = (gn >> 5) & 15, dd = gn & 31;
          size_t dst = (((size_t)(part * 16 + hh) * 32768) + gm) * 32 + dd;
          outb[dst] = f2bf(val);
        } else if (epi == 2) {
          outb[rowbase + gn] = f2bf(gelu_t(val));
        } else {
          size_t idx = rowbase + gn;
          outf[idx] = resf[idx] + val;
        }
      }
    }
  }
}

// ---------------- attention: one wave per (window, head) ----------------
// q/k/v: head-major [h][32768][32] bf16 (contiguous 64x32 tile per win,h)
__global__ __launch_bounds__(64) void attn(const u16* __restrict__ q, const u16* __restrict__ k,
                                           const u16* __restrict__ v, const float* __restrict__ tbl,
                                           u16* __restrict__ ctx) {
  __shared__ __attribute__((aligned(16))) u16 Pl[64 * 80];
  __shared__ __attribute__((aligned(16))) u16 Vt[32 * 72];  // V^T: [dim][token]
  __shared__ float tb[225];
  const int win = blockIdx.x, h = blockIdx.y;
  const int lane = threadIdx.x;
  const int l15 = lane & 15, quad = lane >> 4;

  for (int idx = lane; idx < 225; idx += 64) tb[idx] = tbl[idx * 16 + h];

  const size_t tilebase = ((size_t)h * 32768 + win * 64) * 32;
  const u16* qh = q + tilebase;
  const u16* kh = k + tilebase;
  const u16* vh = v + tilebase;

  // stage V transposed via fully-coalesced b128 loads
#pragma unroll
  for (int rnd = 0; rnd < 4; rnd++) {
    int t = rnd * 16 + (lane >> 2);
    int c = (lane & 3) * 8;
    short8 vrow = ld8(vh + t * 32 + c);
#pragma unroll
    for (int j = 0; j < 8; j++) Vt[(c + j) * 72 + t] = (u16)vrow[j];
  }

  short8 aq[4], bkf[4];
#pragma unroll
  for (int mt = 0; mt < 4; mt++) aq[mt] = ld8(qh + (mt * 16 + l15) * 32 + quad * 8);
#pragma unroll
  for (int nt = 0; nt < 4; nt++) bkf[nt] = ld8(kh + (nt * 16 + l15) * 32 + quad * 8);

  f32x4 zero4 = {0.f, 0.f, 0.f, 0.f};
  f32x4 s[4][4];
#pragma unroll
  for (int i = 0; i < 4; i++)
#pragma unroll
    for (int j = 0; j < 4; j++) s[i][j] = zero4;
#pragma unroll
  for (int mt = 0; mt < 4; mt++)
#pragma unroll
    for (int nt = 0; nt < 4; nt++)
      s[mt][nt] = __builtin_amdgcn_mfma_f32_16x16x32_bf16(aq[mt], bkf[nt], s[mt][nt], 0, 0, 0);

  __syncthreads();  // tb + Vt ready

  const int winin = win & 63;
  const int wrow0 = (winin >> 3) * 8, wcol0 = (winin & 7) * 8;
  int valc[4], ci[4], cj[4];
#pragma unroll
  for (int nt = 0; nt < 4; nt++) {
    int ct = nt * 16 + l15;
    ci[nt] = ct >> 3;
    cj[nt] = ct & 7;
    int rr_ = wrow0 + ci[nt], cc_ = wcol0 + cj[nt];
    valc[nt] = 3 * (rr_ < 56 ? 0 : (rr_ < 60 ? 1 : 2)) + (cc_ < 56 ? 0 : (cc_ < 60 ? 1 : 2));
  }
  const float scale = 0.17677669529663687f;  // 1/sqrt(32)
#pragma unroll
  for (int mt = 0; mt < 4; mt++) {
#pragma unroll
    for (int rr = 0; rr < 4; rr++) {
      int rt = mt * 16 + quad * 4 + rr;
      int i1 = rt >> 3, j1 = rt & 7;
      int rrow = wrow0 + i1, rcol = wcol0 + j1;
      int valr = 3 * (rrow < 56 ? 0 : (rrow < 60 ? 1 : 2)) + (rcol < 56 ? 0 : (rcol < 60 ? 1 : 2));
      float sv[4];
      float sum = 0.f;
      // scores are O(+-10): exp without max-subtraction is safe in fp32
#pragma unroll
      for (int nt = 0; nt < 4; nt++) {
        int idx = (i1 - ci[nt] + 7) * 15 + (j1 - cj[nt] + 7);
        float e = s[mt][nt][rr] * scale + tb[idx] + (valr == valc[nt] ? 0.f : -100.f);
        sv[nt] = __expf(e);
        sum += sv[nt];
      }
#pragma unroll
      for (int m = 1; m < 16; m <<= 1) sum += __shfl_xor(sum, m);
      float inv = 1.f / sum;
#pragma unroll
      for (int nt = 0; nt < 4; nt++) Pl[rt * 80 + nt * 16 + l15] = f2bf(sv[nt] * inv);
    }
  }
  __syncthreads();

  // O = P(64x64) @ V(64x32), V^T from LDS
  f32x4 o[4][2];
#pragma unroll
  for (int i = 0; i < 4; i++)
#pragma unroll
    for (int j = 0; j < 2; j++) o[i][j] = zero4;
#pragma unroll
  for (int kk = 0; kk < 2; kk++) {
    short8 bv2[2];
#pragma unroll
    for (int nt = 0; nt < 2; nt++)
      bv2[nt] = ld8(Vt + (nt * 16 + l15) * 72 + kk * 32 + quad * 8);
#pragma unroll
    for (int mt = 0; mt < 4; mt++) {
      short8 ap = ld8(Pl + (mt * 16 + l15) * 80 + kk * 32 + quad * 8);
#pragma unroll
      for (int nt = 0; nt < 2; nt++)
        o[mt][nt] = __builtin_amdgcn_mfma_f32_16x16x32_bf16(ap, bv2[nt], o[mt][nt], 0, 0, 0);
    }
  }
  const size_t cbase = (size_t)win * 64 * 512 + h * 32;
#pragma unroll
  for (int mt = 0; mt < 4; mt++)
#pragma unroll
    for (int rr = 0; rr < 4; rr++) {
      int rt = mt * 16 + quad * 4 + rr;
#pragma unroll
      for (int nt = 0; nt < 2; nt++)
        ctx[cbase + (size_t)rt * 512 + nt * 16 + l15] = f2bf(o[mt][nt][rr]);
    }
}

extern "C" void kernel_launch(void* const* d_in, const int* in_sizes, int n_in,
                              void* d_out, int out_size, void* d_ws, size_t ws_size,
                              hipStream_t stream) {
  const float* hs   = (const float*)d_in[0];
  const float* ln1g = (const float*)d_in[1];
  const float* ln1b = (const float*)d_in[2];
  const float* wq   = (const float*)d_in[3];
  const float* bq   = (const float*)d_in[4];
  const float* wk   = (const float*)d_in[5];
  const float* bk   = (const float*)d_in[6];
  const float* wvp  = (const float*)d_in[7];
  const float* bv   = (const float*)d_in[8];
  const float* tbl  = (const float*)d_in[9];
  const float* wo   = (const float*)d_in[10];
  const float* bo   = (const float*)d_in[11];
  const float* ln2g = (const float*)d_in[12];
  const float* ln2b = (const float*)d_in[13];
  const float* w1   = (const float*)d_in[14];
  const float* b1   = (const float*)d_in[15];
  const float* w2   = (const float*)d_in[16];
  const float* b2   = (const float*)d_in[17];
  float* out = (float*)d_out;
  u16* ws = (u16*)d_ws;

  const size_t S = (size_t)32768 * 512;
  u16* xw   = ws;          // LN1 out / ctx / LN2 out (bf16, S)
  u16* qb   = ws + S;      // Q head-major [16][32768][32]
  u16* kb   = ws + 2 * S;  // K head-major
  u16* vb   = ws + 3 * S;  // V head-major
  u16* y1   = ws + S;      // MLP intermediate (32768 x 2048 bf16, 4S) after attn
  u16* wt   = ws + 5 * S;  // transposed weights (bf16)
  u16* wqkvT = wt;         // 1536 x 512 (wq^T | wk^T | wv^T rows)
  u16* woT  = wt + 786432;
  u16* w1T  = wt + 1048576;
  u16* w2T  = wt + 2097152;
  float* bcat = (float*)(wt + 3145728);  // 1536 fp32
  float* hid = out;        // residual stream lives in d_out (fp32)

  // fused 4x 512x512 weight transpose (wq,wk,wv,wo) in one launch
  transp4<<<dim3(16, 16, 4), 256, 0, stream>>>(wq, wk, wvp, wo,
                                               wqkvT, wqkvT + 262144, wqkvT + 524288, woT);
  transp<<<dim3(64, 16), 256, 0, stream>>>(w1, w1T, 512, 2048);
  transp<<<dim3(16, 64), 256, 0, stream>>>(w2, w2T, 2048, 512);
  concat_bias<<<6, 256, 0, stream>>>(bq, bk, bv, bcat);

  ln_win<<<8192, 256, 0, stream>>>(hs, ln1g, ln1b, xw, 1);

  // fused QKV: (32768 x 512) @ (512 x 1536) -> head-major Q/K/V at ws+S
  gemm_tb<<<dim3(128, 12), 512, 0, stream>>>(xw, wqkvT, bcat, qb, nullptr, nullptr,
                                             32768, 1536, 512, 0);

  attn<<<dim3(512, 16), 64, 0, stream>>>(qb, kb, vb, tbl, xw);

  // hid = hs + window_reverse(ctx @ Wo + bo)   (fp32, into d_out)
  gemm_tb<<<dim3(128, 4), 512, 0, stream>>>(xw, woT, bo, nullptr, hid, hs,
                                            32768, 512, 512, 1);

  // LN2(hid) -> xw (bf16)
  ln_win<<<8192, 256, 0, stream>>>(hid, ln2g, ln2b, xw, 0);

  // y1 = gelu(LN2 @ w1 + b1), full M
  gemm_tb<<<dim3(128, 16), 512, 0, stream>>>(xw, w1T, b1, y1, nullptr, nullptr,
                                             32768, 2048, 512, 2);
  // out = hid + y1 @ w2T + b2  (fp32, in-place RMW on d_out)
  gemm_tb<<<dim3(128, 4), 512, 0, stream>>>(y1, w2T, b2, nullptr, out, hid,
                                            32768, 512, 2048, 3);
}

// Round 7
// 549.619 us; speedup vs baseline: 1.1716x; 1.0498x over previous
//
#include <hip/hip_runtime.h>

typedef unsigned short u16;
typedef __attribute__((ext_vector_type(8))) short short8;
typedef __attribute__((ext_vector_type(4))) float f32x4;

#define SHIFT_ 4

__device__ __forceinline__ float bf2f(u16 u) {
  unsigned x = ((unsigned)u) << 16;
  return __builtin_bit_cast(float, x);
}
__device__ __forceinline__ u16 f2bf(float f) {
  unsigned u = __builtin_bit_cast(unsigned, f);
  u += 0x7fffu + ((u >> 16) & 1u);
  return (u16)(u >> 16);
}
__device__ __forceinline__ short8 ld8(const u16* p) {
  return *(const short8*)p;
}
__device__ __forceinline__ void gld16(const void* g, void* l) {
  __builtin_amdgcn_global_load_lds(
      (const __attribute__((address_space(1))) unsigned int*)g,
      (__attribute__((address_space(3))) unsigned int*)l, 16, 0, 0);
}
// lean tanh-gelu (exp + rcp form)
__device__ __forceinline__ float gelu_t(float x) {
  float x2 = x * x;
  float u = x * (0.7978845608028654f + 0.0356774081f * x2);
  float t = __expf(u + u);
  float th = 1.f - 2.f * __builtin_amdgcn_rcpf(t + 1.f);
  return 0.5f * x * (1.f + th);
}

// ------ fused 4x transpose + fp32->bf16 (each 512x512), z selects matrix ----
__global__ void transp4(const float* __restrict__ i0, const float* __restrict__ i1,
                        const float* __restrict__ i2, const float* __restrict__ i3,
                        u16* __restrict__ o0, u16* __restrict__ o1,
                        u16* __restrict__ o2, u16* __restrict__ o3) {
  __shared__ u16 t[32][33];
  const float* in;
  u16* out;
  switch (blockIdx.z) {
    case 0: in = i0; out = o0; break;
    case 1: in = i1; out = o1; break;
    case 2: in = i2; out = o2; break;
    default: in = i3; out = o3; break;
  }
  int tx = threadIdx.x & 31, ty = threadIdx.x >> 5;
  int c0 = blockIdx.x * 32, r0 = blockIdx.y * 32;
#pragma unroll
  for (int i = 0; i < 4; i++)
    t[ty + i * 8][tx] = f2bf(in[(size_t)(r0 + ty + i * 8) * 512 + c0 + tx]);
  __syncthreads();
#pragma unroll
  for (int i = 0; i < 4; i++)
    out[(size_t)(c0 + ty + i * 8) * 512 + r0 + tx] = t[tx][ty + i * 8];
}

// ---------------- transpose + fp32->bf16 convert (R x C fp32 -> C x R bf16) --
__global__ void transp(const float* __restrict__ in, u16* __restrict__ out, int R, int C) {
  __shared__ u16 t[32][33];
  int tx = threadIdx.x & 31, ty = threadIdx.x >> 5;
  int c0 = blockIdx.x * 32, r0 = blockIdx.y * 32;
#pragma unroll
  for (int i = 0; i < 4; i++)
    t[ty + i * 8][tx] = f2bf(in[(size_t)(r0 + ty + i * 8) * C + c0 + tx]);
  __syncthreads();
#pragma unroll
  for (int i = 0; i < 4; i++)
    out[(size_t)(c0 + ty + i * 8) * R + r0 + tx] = t[tx][ty + i * 8];
}

__global__ void concat_bias(const float* __restrict__ a, const float* __restrict__ b,
                            const float* __restrict__ c, float* __restrict__ o) {
  int i = blockIdx.x * 256 + threadIdx.x;
  if (i < 512) o[i] = a[i];
  else if (i < 1024) o[i] = b[i - 512];
  else if (i < 1536) o[i] = c[i - 1024];
}

// ---------------- LayerNorm fp32 -> bf16 (optionally fused shift+window) -----
__global__ void ln_win(const float* __restrict__ hid, const float* __restrict__ g,
                       const float* __restrict__ b, u16* __restrict__ out, int windowed) {
  int wv = threadIdx.x >> 6, lane = threadIdx.x & 63;
  int tokid = blockIdx.x * 4 + wv;
  size_t src;
  if (windowed) {
    int t = tokid & 63, w = tokid >> 6;
    int winin = w & 63, bb = w >> 6;
    int r = ((winin >> 3) * 8 + (t >> 3) + SHIFT_) & 63;
    int c = ((winin & 7) * 8 + (t & 7) + SHIFT_) & 63;
    src = ((size_t)bb * 4096 + r * 64 + c) * 512;
  } else {
    src = (size_t)tokid * 512;
  }
  f32x4 x0 = *(const f32x4*)(hid + src + lane * 8);
  f32x4 x1 = *(const f32x4*)(hid + src + lane * 8 + 4);
  float x[8];
#pragma unroll
  for (int e = 0; e < 4; e++) { x[e] = x0[e]; x[e + 4] = x1[e]; }
  float s = 0.f, s2 = 0.f;
#pragma unroll
  for (int e = 0; e < 8; e++) {
    s += x[e];
    s2 += x[e] * x[e];
  }
#pragma unroll
  for (int m = 1; m < 64; m <<= 1) {
    s += __shfl_xor(s, m);
    s2 += __shfl_xor(s2, m);
  }
  float mean = s * (1.f / 512.f);
  float var = s2 * (1.f / 512.f) - mean * mean;
  float rstd = rsqrtf(var + 1e-5f);
  u16 pack[8];
#pragma unroll
  for (int e = 0; e < 8; e++) {
    int c = lane * 8 + e;
    float y = (x[e] - mean) * rstd * g[c] + b[c];
    pack[e] = f2bf(y);
  }
  *(short8*)(out + (size_t)tokid * 512 + lane * 8) = *(const short8*)pack;
}

// ---------------- GEMM (tri-buffer, counted vmcnt): C = A @ Bt^T + bias -----
// Tile 256x128, BK=32, 512 threads (8 waves, 64x64 each). TRIPLE-buffered LDS
// (72KB, 2 blocks/CU), prefetch depth 2, counted vmcnt(3) gates, raw
// s_barrier, setprio around the MFMA cluster. LDS slot swizzle
// (slot_raw + (row>>1)) & 3 -> ds_read_b128 2-way (free).
//
// NEW (r7): XCD-chunked A-panel-major block swizzle. HW dispatches linear
// block ids round-robin over 8 XCDs; we remap so each XCD gets a contiguous
// run of works, and decompose work n-fastest: consecutive works on one XCD
// share the SAME 256-row A panel (0.5-1MB) -> A-stage global_load_lds hits
// L2 (~200cy, covered by prefetch depth 2) instead of HBM (~900cy), and A is
// fetched from HBM ~once instead of ~3x (FETCH_SIZE 97->~55MB on MLP1).
// B (0.5-2MB) stays L2-resident as before. nwg always % 8 == 0 here.
// epi 0: head-major QKV  | epi 1: window-reverse+unshift + residual (fp32)
// epi 2: bf16(gelu(val)) | epi 3: outf = resf + val (fp32)
__global__ __launch_bounds__(512) void gemm_tb(
    const u16* __restrict__ A, const u16* __restrict__ Bt,
    const float* __restrict__ bias, u16* __restrict__ outb, float* __restrict__ outf,
    const float* __restrict__ resf, int M, int N, int K, int epi) {
  constexpr int BUF = (256 + 128) * 32;
  __shared__ __attribute__((aligned(16))) u16 Ls[3 * BUF];
  const int tid = threadIdx.x;
  const int wv = tid >> 6, lane = tid & 63;
  const int l15 = lane & 15, quad = lane >> 4;

  // XCD-chunked, n-fastest work decomposition (bijective: nwg % 8 == 0)
  const int NB = gridDim.y;
  const int nwg = gridDim.x * NB;
  const int linear = blockIdx.y * gridDim.x + blockIdx.x;
  const int chunk = nwg >> 3;
  const int work = (linear & 7) * chunk + (linear >> 3);
  const int mb = work / NB;
  const int nb = work - mb * NB;
  const int m0 = mb * 256, n0 = nb * 128;

  const int wm = (wv >> 1) * 64, wn = (wv & 1) * 64;

  const int arow = tid >> 2;
  const int acol = (((tid & 3) - (tid >> 3)) & 3) * 8;
  const u16* gA = A + (size_t)(m0 + arow) * K + acol;
  const u16* gB = Bt + (size_t)(n0 + arow) * K + acol;
  const int lAoff = tid * 8;
  const int lA2off = 4096 + tid * 8;
  const int lBoff = 8192 + tid * 8;

  f32x4 zero4 = {0.f, 0.f, 0.f, 0.f};
  f32x4 acc[4][4];
#pragma unroll
  for (int i = 0; i < 4; i++)
#pragma unroll
    for (int j = 0; j < 4; j++) acc[i][j] = zero4;

  const int kiter = K >> 5;
  // prologue: stage tiles 0 and 1 into buffers 0 and 1
  {
    gld16(gA, Ls + lAoff);
    gld16(gA + (size_t)128 * K, Ls + lA2off);
    gld16(gB, Ls + lBoff);
    u16* base = Ls + BUF;
    const u16* a = gA + 32;
    gld16(a, base + lAoff);
    gld16(a + (size_t)128 * K, base + lA2off);
    gld16(gB + 32, base + lBoff);
  }
  int ci = 0;
  for (int ko = 0; ko < kiter; ++ko) {
    if (ko + 1 < kiter) {
      asm volatile("s_waitcnt vmcnt(3)" ::: "memory");
    } else {
      asm volatile("s_waitcnt vmcnt(0)" ::: "memory");
    }
    __builtin_amdgcn_s_barrier();
    asm volatile("" ::: "memory");
    if (ko + 2 < kiter) {
      int si = ci + 2;
      if (si >= 3) si -= 3;
      u16* base = Ls + si * BUF;
      const u16* a = gA + (size_t)(ko + 2) * 32;
      gld16(a, base + lAoff);
      gld16(a + (size_t)128 * K, base + lA2off);
      gld16(gB + (size_t)(ko + 2) * 32, base + lBoff);
    }
    const u16* Ab = Ls + ci * BUF;
    const u16* Bb = Ab + 8192;
    short8 af[4], bfr[4];
#pragma unroll
    for (int mt = 0; mt < 4; mt++) {
      int row = wm + mt * 16 + l15;
      af[mt] = ld8(Ab + (row * 4 + ((quad + (row >> 1)) & 3)) * 8);
    }
#pragma unroll
    for (int nt = 0; nt < 4; nt++) {
      int row = wn + nt * 16 + l15;
      bfr[nt] = ld8(Bb + (row * 4 + ((quad + (row >> 1)) & 3)) * 8);
    }
    __builtin_amdgcn_s_setprio(1);
#pragma unroll
    for (int mt = 0; mt < 4; mt++)
#pragma unroll
      for (int nt = 0; nt < 4; nt++)
        acc[mt][nt] = __builtin_amdgcn_mfma_f32_16x16x32_bf16(af[mt], bfr[nt], acc[mt][nt], 0, 0, 0);
    __builtin_amdgcn_s_setprio(0);
    ci = (ci == 2) ? 0 : ci + 1;
  }

  float bvv[4];
#pragma unroll
  for (int nt = 0; nt < 4; nt++) bvv[nt] = bias[n0 + wn + nt * 16 + l15];

#pragma unroll
  for (int mt = 0; mt < 4; mt++) {
#pragma unroll
    for (int rr = 0; rr < 4; rr++) {
      int gm = m0 + wm + mt * 16 + quad * 4 + rr;
      size_t rowbase = 0;
      if (epi == 1) {
        int tok = gm & 63, winin = (gm >> 6) & 63, bb = gm >> 12;
        int sr = (winin >> 3) * 8 + (tok >> 3);
        int sc = (winin & 7) * 8 + (tok & 7);
        int fr = (sr + SHIFT_) & 63, fc = (sc + SHIFT_) & 63;
        rowbase = ((size_t)bb * 4096 + fr * 64 + fc) * 512;
      } else if (epi == 3) {
        rowbase = (size_t)gm * 512;
      } else if (epi == 2) {
        rowbase = (size_t)gm * N;
      }
#pragma unroll
      for (int nt = 0; nt < 4; nt++) {
        int gn = n0 + wn + nt * 16 + l15;
        float val = acc[mt][nt][rr] + bvv[nt];
        if (epi == 0) {
          int part = gn >> 9, hh = (gn >> 5) & 15, dd = gn & 31;
          size_t dst = (((size_t)(part * 16 + hh) * 32768) + gm) * 32 + dd;
          outb[dst] = f2bf(val);
        } else if (epi == 2) {
          outb[rowbase + gn] = f2bf(gelu_t(val));
        } else {
          size_t idx = rowbase + gn;
          outf[idx] = resf[idx] + val;
        }
      }
    }
  }
}

// ---------------- attention: one wave per (window, head) ----------------
// q/k/v: head-major [h][32768][32] bf16 (contiguous 64x32 tile per win,h)
__global__ __launch_bounds__(64) void attn(const u16* __restrict__ q, const u16* __restrict__ k,
                                           const u16* __restrict__ v, const float* __restrict__ tbl,
                                           u16* __restrict__ ctx) {
  __shared__ __attribute__((aligned(16))) u16 Pl[64 * 80];
  __shared__ __attribute__((aligned(16))) u16 Vt[32 * 72];  // V^T: [dim][token]
  __shared__ float tb[225];
  const int win = blockIdx.x, h = blockIdx.y;
  const int lane = threadIdx.x;
  const int l15 = lane & 15, quad = lane >> 4;

  for (int idx = lane; idx < 225; idx += 64) tb[idx] = tbl[idx * 16 + h];

  const size_t tilebase = ((size_t)h * 32768 + win * 64) * 32;
  const u16* qh = q + tilebase;
  const u16* kh = k + tilebase;
  const u16* vh = v + tilebase;

  // stage V transposed via fully-coalesced b128 loads
#pragma unroll
  for (int rnd = 0; rnd < 4; rnd++) {
    int t = rnd * 16 + (lane >> 2);
    int c = (lane & 3) * 8;
    short8 vrow = ld8(vh + t * 32 + c);
#pragma unroll
    for (int j = 0; j < 8; j++) Vt[(c + j) * 72 + t] = (u16)vrow[j];
  }

  short8 aq[4], bkf[4];
#pragma unroll
  for (int mt = 0; mt < 4; mt++) aq[mt] = ld8(qh + (mt * 16 + l15) * 32 + quad * 8);
#pragma unroll
  for (int nt = 0; nt < 4; nt++) bkf[nt] = ld8(kh + (nt * 16 + l15) * 32 + quad * 8);

  f32x4 zero4 = {0.f, 0.f, 0.f, 0.f};
  f32x4 s[4][4];
#pragma unroll
  for (int i = 0; i < 4; i++)
#pragma unroll
    for (int j = 0; j < 4; j++) s[i][j] = zero4;
#pragma unroll
  for (int mt = 0; mt < 4; mt++)
#pragma unroll
    for (int nt = 0; nt < 4; nt++)
      s[mt][nt] = __builtin_amdgcn_mfma_f32_16x16x32_bf16(aq[mt], bkf[nt], s[mt][nt], 0, 0, 0);

  __syncthreads();  // tb + Vt ready

  const int winin = win & 63;
  const int wrow0 = (winin >> 3) * 8, wcol0 = (winin & 7) * 8;
  int valc[4], ci[4], cj[4];
#pragma unroll
  for (int nt = 0; nt < 4; nt++) {
    int ct = nt * 16 + l15;
    ci[nt] = ct >> 3;
    cj[nt] = ct & 7;
    int rr_ = wrow0 + ci[nt], cc_ = wcol0 + cj[nt];
    valc[nt] = 3 * (rr_ < 56 ? 0 : (rr_ < 60 ? 1 : 2)) + (cc_ < 56 ? 0 : (cc_ < 60 ? 1 : 2));
  }
  const float scale = 0.17677669529663687f;  // 1/sqrt(32)
#pragma unroll
  for (int mt = 0; mt < 4; mt++) {
#pragma unroll
    for (int rr = 0; rr < 4; rr++) {
      int rt = mt * 16 + quad * 4 + rr;
      int i1 = rt >> 3, j1 = rt & 7;
      int rrow = wrow0 + i1, rcol = wcol0 + j1;
      int valr = 3 * (rrow < 56 ? 0 : (rrow < 60 ? 1 : 2)) + (rcol < 56 ? 0 : (rcol < 60 ? 1 : 2));
      float sv[4];
      float sum = 0.f;
      // scores are O(+-10): exp without max-subtraction is safe in fp32
#pragma unroll
      for (int nt = 0; nt < 4; nt++) {
        int idx = (i1 - ci[nt] + 7) * 15 + (j1 - cj[nt] + 7);
        float e = s[mt][nt][rr] * scale + tb[idx] + (valr == valc[nt] ? 0.f : -100.f);
        sv[nt] = __expf(e);
        sum += sv[nt];
      }
#pragma unroll
      for (int m = 1; m < 16; m <<= 1) sum += __shfl_xor(sum, m);
      float inv = 1.f / sum;
#pragma unroll
      for (int nt = 0; nt < 4; nt++) Pl[rt * 80 + nt * 16 + l15] = f2bf(sv[nt] * inv);
    }
  }
  __syncthreads();

  // O = P(64x64) @ V(64x32), V^T from LDS
  f32x4 o[4][2];
#pragma unroll
  for (int i = 0; i < 4; i++)
#pragma unroll
    for (int j = 0; j < 2; j++) o[i][j] = zero4;
#pragma unroll
  for (int kk = 0; kk < 2; kk++) {
    short8 bv2[2];
#pragma unroll
    for (int nt = 0; nt < 2; nt++)
      bv2[nt] = ld8(Vt + (nt * 16 + l15) * 72 + kk * 32 + quad * 8);
#pragma unroll
    for (int mt = 0; mt < 4; mt++) {
      short8 ap = ld8(Pl + (mt * 16 + l15) * 80 + kk * 32 + quad * 8);
#pragma unroll
      for (int nt = 0; nt < 2; nt++)
        o[mt][nt] = __builtin_amdgcn_mfma_f32_16x16x32_bf16(ap, bv2[nt], o[mt][nt], 0, 0, 0);
    }
  }
  const size_t cbase = (size_t)win * 64 * 512 + h * 32;
#pragma unroll
  for (int mt = 0; mt < 4; mt++)
#pragma unroll
    for (int rr = 0; rr < 4; rr++) {
      int rt = mt * 16 + quad * 4 + rr;
#pragma unroll
      for (int nt = 0; nt < 2; nt++)
        ctx[cbase + (size_t)rt * 512 + nt * 16 + l15] = f2bf(o[mt][nt][rr]);
    }
}

extern "C" void kernel_launch(void* const* d_in, const int* in_sizes, int n_in,
                              void* d_out, int out_size, void* d_ws, size_t ws_size,
                              hipStream_t stream) {
  const float* hs   = (const float*)d_in[0];
  const float* ln1g = (const float*)d_in[1];
  const float* ln1b = (const float*)d_in[2];
  const float* wq   = (const float*)d_in[3];
  const float* bq   = (const float*)d_in[4];
  const float* wk   = (const float*)d_in[5];
  const float* bk   = (const float*)d_in[6];
  const float* wvp  = (const float*)d_in[7];
  const float* bv   = (const float*)d_in[8];
  const float* tbl  = (const float*)d_in[9];
  const float* wo   = (const float*)d_in[10];
  const float* bo   = (const float*)d_in[11];
  const float* ln2g = (const float*)d_in[12];
  const float* ln2b = (const float*)d_in[13];
  const float* w1   = (const float*)d_in[14];
  const float* b1   = (const float*)d_in[15];
  const float* w2   = (const float*)d_in[16];
  const float* b2   = (const float*)d_in[17];
  float* out = (float*)d_out;
  u16* ws = (u16*)d_ws;

  const size_t S = (size_t)32768 * 512;
  u16* xw   = ws;          // LN1 out / ctx / LN2 out (bf16, S)
  u16* qb   = ws + S;      // Q head-major [16][32768][32]
  u16* kb   = ws + 2 * S;  // K head-major
  u16* vb   = ws + 3 * S;  // V head-major
  u16* y1   = ws + S;      // MLP intermediate (32768 x 2048 bf16, 4S) after attn
  u16* wt   = ws + 5 * S;  // transposed weights (bf16)
  u16* wqkvT = wt;         // 1536 x 512 (wq^T | wk^T | wv^T rows)
  u16* woT  = wt + 786432;
  u16* w1T  = wt + 1048576;
  u16* w2T  = wt + 2097152;
  float* bcat = (float*)(wt + 3145728);  // 1536 fp32
  float* hid = out;        // residual stream lives in d_out (fp32)

  // fused 4x 512x512 weight transpose (wq,wk,wv,wo) in one launch
  transp4<<<dim3(16, 16, 4), 256, 0, stream>>>(wq, wk, wvp, wo,
                                               wqkvT, wqkvT + 262144, wqkvT + 524288, woT);
  transp<<<dim3(64, 16), 256, 0, stream>>>(w1, w1T, 512, 2048);
  transp<<<dim3(16, 64), 256, 0, stream>>>(w2, w2T, 2048, 512);
  concat_bias<<<6, 256, 0, stream>>>(bq, bk, bv, bcat);

  ln_win<<<8192, 256, 0, stream>>>(hs, ln1g, ln1b, xw, 1);

  // fused QKV: (32768 x 512) @ (512 x 1536) -> head-major Q/K/V at ws+S
  gemm_tb<<<dim3(128, 12), 512, 0, stream>>>(xw, wqkvT, bcat, qb, nullptr, nullptr,
                                             32768, 1536, 512, 0);

  attn<<<dim3(512, 16), 64, 0, stream>>>(qb, kb, vb, tbl, xw);

  // hid = hs + window_reverse(ctx @ Wo + bo)   (fp32, into d_out)
  gemm_tb<<<dim3(128, 4), 512, 0, stream>>>(xw, woT, bo, nullptr, hid, hs,
                                            32768, 512, 512, 1);

  // LN2(hid) -> xw (bf16)
  ln_win<<<8192, 256, 0, stream>>>(hid, ln2g, ln2b, xw, 0);

  // y1 = gelu(LN2 @ w1 + b1), full M
  gemm_tb<<<dim3(128, 16), 512, 0, stream>>>(xw, w1T, b1, y1, nullptr, nullptr,
                                             32768, 2048, 512, 2);
  // out = hid + y1 @ w2T + b2  (fp32, in-place RMW on d_out)
  gemm_tb<<<dim3(128, 4), 512, 0, stream>>>(y1, w2T, b2, nullptr, out, hid,
                                            32768, 512, 2048, 3);
}

// Round 8
// 543.692 us; speedup vs baseline: 1.1844x; 1.0109x over previous
//
#include <hip/hip_runtime.h>

typedef unsigned short u16;
typedef __attribute__((ext_vector_type(8))) short short8;
typedef __attribute__((ext_vector_type(4))) float f32x4;

#define SHIFT_ 4

__device__ __forceinline__ float bf2f(u16 u) {
  unsigned x = ((unsigned)u) << 16;
  return __builtin_bit_cast(float, x);
}
__device__ __forceinline__ u16 f2bf(float f) {
  unsigned u = __builtin_bit_cast(unsigned, f);
  u += 0x7fffu + ((u >> 16) & 1u);
  return (u16)(u >> 16);
}
__device__ __forceinline__ short8 ld8(const u16* p) {
  return *(const short8*)p;
}
__device__ __forceinline__ void gld16(const void* g, void* l) {
  __builtin_amdgcn_global_load_lds(
      (const __attribute__((address_space(1))) unsigned int*)g,
      (__attribute__((address_space(3))) unsigned int*)l, 16, 0, 0);
}
// lean tanh-gelu (exp + rcp form)
__device__ __forceinline__ float gelu_t(float x) {
  float x2 = x * x;
  float u = x * (0.7978845608028654f + 0.0356774081f * x2);
  float t = __expf(u + u);
  float th = 1.f - 2.f * __builtin_amdgcn_rcpf(t + 1.f);
  return 0.5f * x * (1.f + th);
}

// ------ fused 4x transpose + fp32->bf16 (each 512x512), z selects matrix ----
__global__ void transp4(const float* __restrict__ i0, const float* __restrict__ i1,
                        const float* __restrict__ i2, const float* __restrict__ i3,
                        u16* __restrict__ o0, u16* __restrict__ o1,
                        u16* __restrict__ o2, u16* __restrict__ o3) {
  __shared__ u16 t[32][33];
  const float* in;
  u16* out;
  switch (blockIdx.z) {
    case 0: in = i0; out = o0; break;
    case 1: in = i1; out = o1; break;
    case 2: in = i2; out = o2; break;
    default: in = i3; out = o3; break;
  }
  int tx = threadIdx.x & 31, ty = threadIdx.x >> 5;
  int c0 = blockIdx.x * 32, r0 = blockIdx.y * 32;
#pragma unroll
  for (int i = 0; i < 4; i++)
    t[ty + i * 8][tx] = f2bf(in[(size_t)(r0 + ty + i * 8) * 512 + c0 + tx]);
  __syncthreads();
#pragma unroll
  for (int i = 0; i < 4; i++)
    out[(size_t)(c0 + ty + i * 8) * 512 + r0 + tx] = t[tx][ty + i * 8];
}

// ---------------- transpose + fp32->bf16 convert (R x C fp32 -> C x R bf16) --
__global__ void transp(const float* __restrict__ in, u16* __restrict__ out, int R, int C) {
  __shared__ u16 t[32][33];
  int tx = threadIdx.x & 31, ty = threadIdx.x >> 5;
  int c0 = blockIdx.x * 32, r0 = blockIdx.y * 32;
#pragma unroll
  for (int i = 0; i < 4; i++)
    t[ty + i * 8][tx] = f2bf(in[(size_t)(r0 + ty + i * 8) * C + c0 + tx]);
  __syncthreads();
#pragma unroll
  for (int i = 0; i < 4; i++)
    out[(size_t)(c0 + ty + i * 8) * R + r0 + tx] = t[tx][ty + i * 8];
}

__global__ void concat_bias(const float* __restrict__ a, const float* __restrict__ b,
                            const float* __restrict__ c, float* __restrict__ o) {
  int i = blockIdx.x * 256 + threadIdx.x;
  if (i < 512) o[i] = a[i];
  else if (i < 1024) o[i] = b[i - 512];
  else if (i < 1536) o[i] = c[i - 1024];
}

// ---------------- LayerNorm fp32 -> bf16 (optionally fused shift+window) -----
__global__ void ln_win(const float* __restrict__ hid, const float* __restrict__ g,
                       const float* __restrict__ b, u16* __restrict__ out, int windowed) {
  int wv = threadIdx.x >> 6, lane = threadIdx.x & 63;
  int tokid = blockIdx.x * 4 + wv;
  size_t src;
  if (windowed) {
    int t = tokid & 63, w = tokid >> 6;
    int winin = w & 63, bb = w >> 6;
    int r = ((winin >> 3) * 8 + (t >> 3) + SHIFT_) & 63;
    int c = ((winin & 7) * 8 + (t & 7) + SHIFT_) & 63;
    src = ((size_t)bb * 4096 + r * 64 + c) * 512;
  } else {
    src = (size_t)tokid * 512;
  }
  f32x4 x0 = *(const f32x4*)(hid + src + lane * 8);
  f32x4 x1 = *(const f32x4*)(hid + src + lane * 8 + 4);
  float x[8];
#pragma unroll
  for (int e = 0; e < 4; e++) { x[e] = x0[e]; x[e + 4] = x1[e]; }
  float s = 0.f, s2 = 0.f;
#pragma unroll
  for (int e = 0; e < 8; e++) {
    s += x[e];
    s2 += x[e] * x[e];
  }
#pragma unroll
  for (int m = 1; m < 64; m <<= 1) {
    s += __shfl_xor(s, m);
    s2 += __shfl_xor(s2, m);
  }
  float mean = s * (1.f / 512.f);
  float var = s2 * (1.f / 512.f) - mean * mean;
  float rstd = rsqrtf(var + 1e-5f);
  u16 pack[8];
#pragma unroll
  for (int e = 0; e < 8; e++) {
    int c = lane * 8 + e;
    float y = (x[e] - mean) * rstd * g[c] + b[c];
    pack[e] = f2bf(y);
  }
  *(short8*)(out + (size_t)tokid * 512 + lane * 8) = *(const short8*)pack;
}

// ---------------- GEMM (dbuf 48KB, 3 blocks/CU): C = A @ Bt^T + bias --------
// Tile 256x128, BK=32, 512 threads (8 waves, 64x64 each). DOUBLE-buffered LDS
// (48KB -> 3 blocks/CU, 24 waves — max TLP of this family), raw s_barrier with
// vmcnt(0) gate (with dbuf, the FIFO at the gate holds exactly the current
// tile's 3 loads, issued one full K-step earlier -> gate is a counted wait in
// disguise; no blanket lgkm drain like __syncthreads), setprio around MFMA.
// LDS slot swizzle (slot_raw + (row>>1)) & 3 -> ds_read_b128 2-way (free).
// Race-freedom of post-barrier stage: stage(ko+1) overwrites tile ko-1's
// buffer; all waves' tile-(ko-1) reads retired before they arrive at step
// ko's barrier; stage issued only after that barrier.
//
// XCD-chunked A-panel-major block swizzle (r7, FETCH 97->50MB on MLP1):
// linear ids round-robin over 8 XCDs; remap so each XCD gets a contiguous
// run of works, n-fastest -> consecutive works on one XCD share the same
// 256-row A panel -> A stages hit L2 (~200-400cy, covered by the 1-step
// issue distance). nwg always % 8 == 0 here.
// epi 0: head-major QKV  | epi 1: window-reverse+unshift + residual (fp32)
// epi 2: bf16(gelu(val)) | epi 3: outf = resf + val (fp32)
__global__ __launch_bounds__(512) void gemm_tb(
    const u16* __restrict__ A, const u16* __restrict__ Bt,
    const float* __restrict__ bias, u16* __restrict__ outb, float* __restrict__ outf,
    const float* __restrict__ resf, int M, int N, int K, int epi) {
  constexpr int BUF = (256 + 128) * 32;  // 12288 u16 = 24 KB
  __shared__ __attribute__((aligned(16))) u16 Ls[2 * BUF];
  const int tid = threadIdx.x;
  const int wv = tid >> 6, lane = tid & 63;
  const int l15 = lane & 15, quad = lane >> 4;

  // XCD-chunked, n-fastest work decomposition (bijective: nwg % 8 == 0)
  const int NB = gridDim.y;
  const int nwg = gridDim.x * NB;
  const int linear = blockIdx.y * gridDim.x + blockIdx.x;
  const int chunk = nwg >> 3;
  const int work = (linear & 7) * chunk + (linear >> 3);
  const int mb = work / NB;
  const int nb = work - mb * NB;
  const int m0 = mb * 256, n0 = nb * 128;

  const int wm = (wv >> 1) * 64, wn = (wv & 1) * 64;

  const int arow = tid >> 2;
  const int acol = (((tid & 3) - (tid >> 3)) & 3) * 8;
  const u16* gA = A + (size_t)(m0 + arow) * K + acol;
  const u16* gB = Bt + (size_t)(n0 + arow) * K + acol;
  const int lAoff = tid * 8;
  const int lA2off = 4096 + tid * 8;
  const int lBoff = 8192 + tid * 8;

  // bias before the loop; gate is vmcnt(0) so no count bookkeeping needed
  float bvv[4];
#pragma unroll
  for (int nt = 0; nt < 4; nt++) bvv[nt] = bias[n0 + wn + nt * 16 + l15];

  // precomputed swizzled LDS read offsets (u16 units, loop-invariant)
  int aoff[4], boff[4];
#pragma unroll
  for (int mt = 0; mt < 4; mt++) {
    int row = wm + mt * 16 + l15;
    aoff[mt] = (row * 4 + ((quad + (row >> 1)) & 3)) * 8;
  }
#pragma unroll
  for (int nt = 0; nt < 4; nt++) {
    int row = wn + nt * 16 + l15;
    boff[nt] = 8192 + (row * 4 + ((quad + (row >> 1)) & 3)) * 8;
  }

  f32x4 zero4 = {0.f, 0.f, 0.f, 0.f};
  f32x4 acc[4][4];
#pragma unroll
  for (int i = 0; i < 4; i++)
#pragma unroll
    for (int j = 0; j < 4; j++) acc[i][j] = zero4;

  const int kiter = K >> 5;
  // prologue: stage tile 0 into buffer 0
  {
    gld16(gA, Ls + lAoff);
    gld16(gA + (size_t)128 * K, Ls + lA2off);
    gld16(gB, Ls + lBoff);
  }
  int p = 0;
  for (int ko = 0; ko < kiter; ++ko) {
    // gate: tile ko resident (its 3 loads are the only VMEM in flight)
    asm volatile("s_waitcnt vmcnt(0)" ::: "memory");
    __builtin_amdgcn_s_barrier();
    asm volatile("" ::: "memory");
    if (ko + 1 < kiter) {
      u16* base = Ls + (p ^ 1) * BUF;
      const u16* a = gA + (size_t)(ko + 1) * 32;
      gld16(a, base + lAoff);
      gld16(a + (size_t)128 * K, base + lA2off);
      gld16(gB + (size_t)(ko + 1) * 32, base + lBoff);
    }
    const u16* Ab = Ls + p * BUF;
    short8 af[4], bfr[4];
#pragma unroll
    for (int mt = 0; mt < 4; mt++) af[mt] = ld8(Ab + aoff[mt]);
#pragma unroll
    for (int nt = 0; nt < 4; nt++) bfr[nt] = ld8(Ab + boff[nt]);
    __builtin_amdgcn_s_setprio(1);
#pragma unroll
    for (int mt = 0; mt < 4; mt++)
#pragma unroll
      for (int nt = 0; nt < 4; nt++)
        acc[mt][nt] = __builtin_amdgcn_mfma_f32_16x16x32_bf16(af[mt], bfr[nt], acc[mt][nt], 0, 0, 0);
    __builtin_amdgcn_s_setprio(0);
    p ^= 1;
  }

#pragma unroll
  for (int mt = 0; mt < 4; mt++) {
#pragma unroll
    for (int rr = 0; rr < 4; rr++) {
      int gm = m0 + wm + mt * 16 + quad * 4 + rr;
      size_t rowbase = 0;
      if (epi == 1) {
        int tok = gm & 63, winin = (gm >> 6) & 63, bb = gm >> 12;
        int sr = (winin >> 3) * 8 + (tok >> 3);
        int sc = (winin & 7) * 8 + (tok & 7);
        int fr = (sr + SHIFT_) & 63, fc = (sc + SHIFT_) & 63;
        rowbase = ((size_t)bb * 4096 + fr * 64 + fc) * 512;
      } else if (epi == 3) {
        rowbase = (size_t)gm * 512;
      } else if (epi == 2) {
        rowbase = (size_t)gm * N;
      }
#pragma unroll
      for (int nt = 0; nt < 4; nt++) {
        int gn = n0 + wn + nt * 16 + l15;
        float val = acc[mt][nt][rr] + bvv[nt];
        if (epi == 0) {
          int part = gn >> 9, hh = (gn >> 5) & 15, dd = gn & 31;
          size_t dst = (((size_t)(part * 16 + hh) * 32768) + gm) * 32 + dd;
          outb[dst] = f2bf(val);
        } else if (epi == 2) {
          outb[rowbase + gn] = f2bf(gelu_t(val));
        } else {
          size_t idx = rowbase + gn;
          outf[idx] = resf[idx] + val;
        }
      }
    }
  }
}

// ---------------- attention: one wave per (window, head) ----------------
// q/k/v: head-major [h][32768][32] bf16 (contiguous 64x32 tile per win,h)
__global__ __launch_bounds__(64) void attn(const u16* __restrict__ q, const u16* __restrict__ k,
                                           const u16* __restrict__ v, const float* __restrict__ tbl,
                                           u16* __restrict__ ctx) {
  __shared__ __attribute__((aligned(16))) u16 Pl[64 * 80];
  __shared__ __attribute__((aligned(16))) u16 Vt[32 * 72];  // V^T: [dim][token]
  __shared__ float tb[225];
  const int win = blockIdx.x, h = blockIdx.y;
  const int lane = threadIdx.x;
  const int l15 = lane & 15, quad = lane >> 4;

  for (int idx = lane; idx < 225; idx += 64) tb[idx] = tbl[idx * 16 + h];

  const size_t tilebase = ((size_t)h * 32768 + win * 64) * 32;
  const u16* qh = q + tilebase;
  const u16* kh = k + tilebase;
  const u16* vh = v + tilebase;

  // stage V transposed via fully-coalesced b128 loads
#pragma unroll
  for (int rnd = 0; rnd < 4; rnd++) {
    int t = rnd * 16 + (lane >> 2);
    int c = (lane & 3) * 8;
    short8 vrow = ld8(vh + t * 32 + c);
#pragma unroll
    for (int j = 0; j < 8; j++) Vt[(c + j) * 72 + t] = (u16)vrow[j];
  }

  short8 aq[4], bkf[4];
#pragma unroll
  for (int mt = 0; mt < 4; mt++) aq[mt] = ld8(qh + (mt * 16 + l15) * 32 + quad * 8);
#pragma unroll
  for (int nt = 0; nt < 4; nt++) bkf[nt] = ld8(kh + (nt * 16 + l15) * 32 + quad * 8);

  f32x4 zero4 = {0.f, 0.f, 0.f, 0.f};
  f32x4 s[4][4];
#pragma unroll
  for (int i = 0; i < 4; i++)
#pragma unroll
    for (int j = 0; j < 4; j++) s[i][j] = zero4;
#pragma unroll
  for (int mt = 0; mt < 4; mt++)
#pragma unroll
    for (int nt = 0; nt < 4; nt++)
      s[mt][nt] = __builtin_amdgcn_mfma_f32_16x16x32_bf16(aq[mt], bkf[nt], s[mt][nt], 0, 0, 0);

  __syncthreads();  // tb + Vt ready

  const int winin = win & 63;
  const int wrow0 = (winin >> 3) * 8, wcol0 = (winin & 7) * 8;
  int valc[4], ci[4], cj[4];
#pragma unroll
  for (int nt = 0; nt < 4; nt++) {
    int ct = nt * 16 + l15;
    ci[nt] = ct >> 3;
    cj[nt] = ct & 7;
    int rr_ = wrow0 + ci[nt], cc_ = wcol0 + cj[nt];
    valc[nt] = 3 * (rr_ < 56 ? 0 : (rr_ < 60 ? 1 : 2)) + (cc_ < 56 ? 0 : (cc_ < 60 ? 1 : 2));
  }
  const float scale = 0.17677669529663687f;  // 1/sqrt(32)
#pragma unroll
  for (int mt = 0; mt < 4; mt++) {
#pragma unroll
    for (int rr = 0; rr < 4; rr++) {
      int rt = mt * 16 + quad * 4 + rr;
      int i1 = rt >> 3, j1 = rt & 7;
      int rrow = wrow0 + i1, rcol = wcol0 + j1;
      int valr = 3 * (rrow < 56 ? 0 : (rrow < 60 ? 1 : 2)) + (rcol < 56 ? 0 : (rcol < 60 ? 1 : 2));
      float sv[4];
      float sum = 0.f;
      // scores are O(+-10): exp without max-subtraction is safe in fp32
#pragma unroll
      for (int nt = 0; nt < 4; nt++) {
        int idx = (i1 - ci[nt] + 7) * 15 + (j1 - cj[nt] + 7);
        float e = s[mt][nt][rr] * scale + tb[idx] + (valr == valc[nt] ? 0.f : -100.f);
        sv[nt] = __expf(e);
        sum += sv[nt];
      }
#pragma unroll
      for (int m = 1; m < 16; m <<= 1) sum += __shfl_xor(sum, m);
      float inv = 1.f / sum;
#pragma unroll
      for (int nt = 0; nt < 4; nt++) Pl[rt * 80 + nt * 16 + l15] = f2bf(sv[nt] * inv);
    }
  }
  __syncthreads();

  // O = P(64x64) @ V(64x32), V^T from LDS
  f32x4 o[4][2];
#pragma unroll
  for (int i = 0; i < 4; i++)
#pragma unroll
    for (int j = 0; j < 2; j++) o[i][j] = zero4;
#pragma unroll
  for (int kk = 0; kk < 2; kk++) {
    short8 bv2[2];
#pragma unroll
    for (int nt = 0; nt < 2; nt++)
      bv2[nt] = ld8(Vt + (nt * 16 + l15) * 72 + kk * 32 + quad * 8);
#pragma unroll
    for (int mt = 0; mt < 4; mt++) {
      short8 ap = ld8(Pl + (mt * 16 + l15) * 80 + kk * 32 + quad * 8);
#pragma unroll
      for (int nt = 0; nt < 2; nt++)
        o[mt][nt] = __builtin_amdgcn_mfma_f32_16x16x32_bf16(ap, bv2[nt], o[mt][nt], 0, 0, 0);
    }
  }
  const size_t cbase = (size_t)win * 64 * 512 + h * 32;
#pragma unroll
  for (int mt = 0; mt < 4; mt++)
#pragma unroll
    for (int rr = 0; rr < 4; rr++) {
      int rt = mt * 16 + quad * 4 + rr;
#pragma unroll
      for (int nt = 0; nt < 2; nt++)
        ctx[cbase + (size_t)rt * 512 + nt * 16 + l15] = f2bf(o[mt][nt][rr]);
    }
}

extern "C" void kernel_launch(void* const* d_in, const int* in_sizes, int n_in,
                              void* d_out, int out_size, void* d_ws, size_t ws_size,
                              hipStream_t stream) {
  const float* hs   = (const float*)d_in[0];
  const float* ln1g = (const float*)d_in[1];
  const float* ln1b = (const float*)d_in[2];
  const float* wq   = (const float*)d_in[3];
  const float* bq   = (const float*)d_in[4];
  const float* wk   = (const float*)d_in[5];
  const float* bk   = (const float*)d_in[6];
  const float* wvp  = (const float*)d_in[7];
  const float* bv   = (const float*)d_in[8];
  const float* tbl  = (const float*)d_in[9];
  const float* wo   = (const float*)d_in[10];
  const float* bo   = (const float*)d_in[11];
  const float* ln2g = (const float*)d_in[12];
  const float* ln2b = (const float*)d_in[13];
  const float* w1   = (const float*)d_in[14];
  const float* b1   = (const float*)d_in[15];
  const float* w2   = (const float*)d_in[16];
  const float* b2   = (const float*)d_in[17];
  float* out = (float*)d_out;
  u16* ws = (u16*)d_ws;

  const size_t S = (size_t)32768 * 512;
  u16* xw   = ws;          // LN1 out / ctx / LN2 out (bf16, S)
  u16* qb   = ws + S;      // Q head-major [16][32768][32]
  u16* kb   = ws + 2 * S;  // K head-major
  u16* vb   = ws + 3 * S;  // V head-major
  u16* y1   = ws + S;      // MLP intermediate (32768 x 2048 bf16, 4S) after attn
  u16* wt   = ws + 5 * S;  // transposed weights (bf16)
  u16* wqkvT = wt;         // 1536 x 512 (wq^T | wk^T | wv^T rows)
  u16* woT  = wt + 786432;
  u16* w1T  = wt + 1048576;
  u16* w2T  = wt + 2097152;
  float* bcat = (float*)(wt + 3145728);  // 1536 fp32
  float* hid = out;        // residual stream lives in d_out (fp32)

  // fused 4x 512x512 weight transpose (wq,wk,wv,wo) in one launch
  transp4<<<dim3(16, 16, 4), 256, 0, stream>>>(wq, wk, wvp, wo,
                                               wqkvT, wqkvT + 262144, wqkvT + 524288, woT);
  transp<<<dim3(64, 16), 256, 0, stream>>>(w1, w1T, 512, 2048);
  transp<<<dim3(16, 64), 256, 0, stream>>>(w2, w2T, 2048, 512);
  concat_bias<<<6, 256, 0, stream>>>(bq, bk, bv, bcat);

  ln_win<<<8192, 256, 0, stream>>>(hs, ln1g, ln1b, xw, 1);

  // fused QKV: (32768 x 512) @ (512 x 1536) -> head-major Q/K/V at ws+S
  gemm_tb<<<dim3(128, 12), 512, 0, stream>>>(xw, wqkvT, bcat, qb, nullptr, nullptr,
                                             32768, 1536, 512, 0);

  attn<<<dim3(512, 16), 64, 0, stream>>>(qb, kb, vb, tbl, xw);

  // hid = hs + window_reverse(ctx @ Wo + bo)   (fp32, into d_out)
  gemm_tb<<<dim3(128, 4), 512, 0, stream>>>(xw, woT, bo, nullptr, hid, hs,
                                            32768, 512, 512, 1);

  // LN2(hid) -> xw (bf16)
  ln_win<<<8192, 256, 0, stream>>>(hid, ln2g, ln2b, xw, 0);

  // y1 = gelu(LN2 @ w1 + b1), full M
  gemm_tb<<<dim3(128, 16), 512, 0, stream>>>(xw, w1T, b1, y1, nullptr, nullptr,
                                             32768, 2048, 512, 2);
  // out = hid + y1 @ w2T + b2  (fp32, in-place RMW on d_out)
  gemm_tb<<<dim3(128, 4), 512, 0, stream>>>(y1, w2T, b2, nullptr, out, hid,
                                            32768, 512, 2048, 3);
}

// Round 9
// 524.707 us; speedup vs baseline: 1.2272x; 1.0362x over previous
//
#include <hip/hip_runtime.h>

typedef unsigned short u16;
typedef __attribute__((ext_vector_type(8))) short short8;
typedef __attribute__((ext_vector_type(4))) float f32x4;

#define SHIFT_ 4

__device__ __forceinline__ float bf2f(u16 u) {
  unsigned x = ((unsigned)u) << 16;
  return __builtin_bit_cast(float, x);
}
__device__ __forceinline__ u16 f2bf(float f) {
  unsigned u = __builtin_bit_cast(unsigned, f);
  u += 0x7fffu + ((u >> 16) & 1u);
  return (u16)(u >> 16);
}
__device__ __forceinline__ short8 ld8(const u16* p) {
  return *(const short8*)p;
}
__device__ __forceinline__ void gld16(const void* g, void* l) {
  __builtin_amdgcn_global_load_lds(
      (const __attribute__((address_space(1))) unsigned int*)g,
      (__attribute__((address_space(3))) unsigned int*)l, 16, 0, 0);
}
// lean tanh-gelu (exp + rcp form)
__device__ __forceinline__ float gelu_t(float x) {
  float x2 = x * x;
  float u = x * (0.7978845608028654f + 0.0356774081f * x2);
  float t = __expf(u + u);
  float th = 1.f - 2.f * __builtin_amdgcn_rcpf(t + 1.f);
  return 0.5f * x * (1.f + th);
}

// ------ fused 4x transpose + fp32->bf16 (each 512x512), z selects matrix ----
__global__ void transp4(const float* __restrict__ i0, const float* __restrict__ i1,
                        const float* __restrict__ i2, const float* __restrict__ i3,
                        u16* __restrict__ o0, u16* __restrict__ o1,
                        u16* __restrict__ o2, u16* __restrict__ o3) {
  __shared__ u16 t[32][33];
  const float* in;
  u16* out;
  switch (blockIdx.z) {
    case 0: in = i0; out = o0; break;
    case 1: in = i1; out = o1; break;
    case 2: in = i2; out = o2; break;
    default: in = i3; out = o3; break;
  }
  int tx = threadIdx.x & 31, ty = threadIdx.x >> 5;
  int c0 = blockIdx.x * 32, r0 = blockIdx.y * 32;
#pragma unroll
  for (int i = 0; i < 4; i++)
    t[ty + i * 8][tx] = f2bf(in[(size_t)(r0 + ty + i * 8) * 512 + c0 + tx]);
  __syncthreads();
#pragma unroll
  for (int i = 0; i < 4; i++)
    out[(size_t)(c0 + ty + i * 8) * 512 + r0 + tx] = t[tx][ty + i * 8];
}

// ---------------- transpose + fp32->bf16 convert (R x C fp32 -> C x R bf16) --
__global__ void transp(const float* __restrict__ in, u16* __restrict__ out, int R, int C) {
  __shared__ u16 t[32][33];
  int tx = threadIdx.x & 31, ty = threadIdx.x >> 5;
  int c0 = blockIdx.x * 32, r0 = blockIdx.y * 32;
#pragma unroll
  for (int i = 0; i < 4; i++)
    t[ty + i * 8][tx] = f2bf(in[(size_t)(r0 + ty + i * 8) * C + c0 + tx]);
  __syncthreads();
#pragma unroll
  for (int i = 0; i < 4; i++)
    out[(size_t)(c0 + ty + i * 8) * R + r0 + tx] = t[tx][ty + i * 8];
}

__global__ void concat_bias(const float* __restrict__ a, const float* __restrict__ b,
                            const float* __restrict__ c, float* __restrict__ o) {
  int i = blockIdx.x * 256 + threadIdx.x;
  if (i < 512) o[i] = a[i];
  else if (i < 1024) o[i] = b[i - 512];
  else if (i < 1536) o[i] = c[i - 1024];
}

// ---------------- LayerNorm fp32 -> bf16 (optionally fused shift+window) -----
__global__ void ln_win(const float* __restrict__ hid, const float* __restrict__ g,
                       const float* __restrict__ b, u16* __restrict__ out, int windowed) {
  int wv = threadIdx.x >> 6, lane = threadIdx.x & 63;
  int tokid = blockIdx.x * 4 + wv;
  size_t src;
  if (windowed) {
    int t = tokid & 63, w = tokid >> 6;
    int winin = w & 63, bb = w >> 6;
    int r = ((winin >> 3) * 8 + (t >> 3) + SHIFT_) & 63;
    int c = ((winin & 7) * 8 + (t & 7) + SHIFT_) & 63;
    src = ((size_t)bb * 4096 + r * 64 + c) * 512;
  } else {
    src = (size_t)tokid * 512;
  }
  f32x4 x0 = *(const f32x4*)(hid + src + lane * 8);
  f32x4 x1 = *(const f32x4*)(hid + src + lane * 8 + 4);
  float x[8];
#pragma unroll
  for (int e = 0; e < 4; e++) { x[e] = x0[e]; x[e + 4] = x1[e]; }
  float s = 0.f, s2 = 0.f;
#pragma unroll
  for (int e = 0; e < 8; e++) {
    s += x[e];
    s2 += x[e] * x[e];
  }
#pragma unroll
  for (int m = 1; m < 64; m <<= 1) {
    s += __shfl_xor(s, m);
    s2 += __shfl_xor(s2, m);
  }
  float mean = s * (1.f / 512.f);
  float var = s2 * (1.f / 512.f) - mean * mean;
  float rstd = rsqrtf(var + 1e-5f);
  u16 pack[8];
#pragma unroll
  for (int e = 0; e < 8; e++) {
    int c = lane * 8 + e;
    float y = (x[e] - mean) * rstd * g[c] + b[c];
    pack[e] = f2bf(y);
  }
  *(short8*)(out + (size_t)tokid * 512 + lane * 8) = *(const short8*)pack;
}

// ---------------- GEMM (dbuf 48KB): C = A @ Bt^T + bias ---------------------
// Tile 256x128, BK=32, 512 threads (8 waves, 64x64 each). Double-buffered LDS
// (48KB), raw s_barrier with vmcnt(0) gate (FIFO holds exactly the current
// tile's 3 loads at the gate -> counted wait in disguise; no blanket lgkm
// drain), setprio around MFMA. LDS slot swizzle (slot_raw + (row>>1)) & 3 ->
// ds_read_b128 2-way (free). XCD-chunked A-panel-major block swizzle (r7,
// FETCH 97->50MB on MLP1): each XCD gets a contiguous n-fastest run of works
// so consecutive works share the same 256-row A panel -> A stages hit L2.
//
// NEW (r9): coalesced LDS-staged epilogue for the bf16 outputs (epi 0/2).
// Old path: 64 scalar u16 stores/thread, each wave-instr scattering into
// 4x32B segments (quad selects 4 rows), plus per-output address VALU ->
// VALUBusy ~40% with MfmaUtil ~20%. New path: 4 rounds over mt; round =
// {write 16 f32 (bias applied) into Ls scratch [64][132] f32 (33KB, reuse of
// the K-loop buffers; pad 132 -> ~2-way banks) ; barrier ; read 16 contiguous
// f32 per thread, gelu/pack, TWO b128 stores of 32B fully-contiguous}.
// 8 stores/thread instead of 64; one address computation per round.
// epi 1/3 (fp32 + residual RMW) keep the direct path.
// epi 0: head-major QKV  | epi 1: window-reverse+unshift + residual (fp32)
// epi 2: bf16(gelu(val)) | epi 3: outf = resf + val (fp32)
__global__ __launch_bounds__(512) void gemm_tb(
    const u16* __restrict__ A, const u16* __restrict__ Bt,
    const float* __restrict__ bias, u16* __restrict__ outb, float* __restrict__ outf,
    const float* __restrict__ resf, int M, int N, int K, int epi) {
  constexpr int BUF = (256 + 128) * 32;  // 12288 u16 = 24 KB
  __shared__ __attribute__((aligned(16))) u16 Ls[2 * BUF];
  const int tid = threadIdx.x;
  const int wv = tid >> 6, lane = tid & 63;
  const int l15 = lane & 15, quad = lane >> 4;

  // XCD-chunked, n-fastest work decomposition (bijective: nwg % 8 == 0)
  const int NB = gridDim.y;
  const int nwg = gridDim.x * NB;
  const int linear = blockIdx.y * gridDim.x + blockIdx.x;
  const int chunk = nwg >> 3;
  const int work = (linear & 7) * chunk + (linear >> 3);
  const int mb = work / NB;
  const int nb = work - mb * NB;
  const int m0 = mb * 256, n0 = nb * 128;

  const int wm = (wv >> 1) * 64, wn = (wv & 1) * 64;

  const int arow = tid >> 2;
  const int acol = (((tid & 3) - (tid >> 3)) & 3) * 8;
  const u16* gA = A + (size_t)(m0 + arow) * K + acol;
  const u16* gB = Bt + (size_t)(n0 + arow) * K + acol;
  const int lAoff = tid * 8;
  const int lA2off = 4096 + tid * 8;
  const int lBoff = 8192 + tid * 8;

  // bias before the loop; gate is vmcnt(0) so no count bookkeeping needed
  float bvv[4];
#pragma unroll
  for (int nt = 0; nt < 4; nt++) bvv[nt] = bias[n0 + wn + nt * 16 + l15];

  // precomputed swizzled LDS read offsets (u16 units, loop-invariant)
  int aoff[4], boff[4];
#pragma unroll
  for (int mt = 0; mt < 4; mt++) {
    int row = wm + mt * 16 + l15;
    aoff[mt] = (row * 4 + ((quad + (row >> 1)) & 3)) * 8;
  }
#pragma unroll
  for (int nt = 0; nt < 4; nt++) {
    int row = wn + nt * 16 + l15;
    boff[nt] = 8192 + (row * 4 + ((quad + (row >> 1)) & 3)) * 8;
  }

  f32x4 zero4 = {0.f, 0.f, 0.f, 0.f};
  f32x4 acc[4][4];
#pragma unroll
  for (int i = 0; i < 4; i++)
#pragma unroll
    for (int j = 0; j < 4; j++) acc[i][j] = zero4;

  const int kiter = K >> 5;
  // prologue: stage tile 0 into buffer 0
  {
    gld16(gA, Ls + lAoff);
    gld16(gA + (size_t)128 * K, Ls + lA2off);
    gld16(gB, Ls + lBoff);
  }
  int p = 0;
  for (int ko = 0; ko < kiter; ++ko) {
    // gate: tile ko resident (its 3 loads are the only VMEM in flight)
    asm volatile("s_waitcnt vmcnt(0)" ::: "memory");
    __builtin_amdgcn_s_barrier();
    asm volatile("" ::: "memory");
    if (ko + 1 < kiter) {
      u16* base = Ls + (p ^ 1) * BUF;
      const u16* a = gA + (size_t)(ko + 1) * 32;
      gld16(a, base + lAoff);
      gld16(a + (size_t)128 * K, base + lA2off);
      gld16(gB + (size_t)(ko + 1) * 32, base + lBoff);
    }
    const u16* Ab = Ls + p * BUF;
    short8 af[4], bfr[4];
#pragma unroll
    for (int mt = 0; mt < 4; mt++) af[mt] = ld8(Ab + aoff[mt]);
#pragma unroll
    for (int nt = 0; nt < 4; nt++) bfr[nt] = ld8(Ab + boff[nt]);
    __builtin_amdgcn_s_setprio(1);
#pragma unroll
    for (int mt = 0; mt < 4; mt++)
#pragma unroll
      for (int nt = 0; nt < 4; nt++)
        acc[mt][nt] = __builtin_amdgcn_mfma_f32_16x16x32_bf16(af[mt], bfr[nt], acc[mt][nt], 0, 0, 0);
    __builtin_amdgcn_s_setprio(0);
    p ^= 1;
  }

  if (epi == 0 || epi == 2) {
    // coalesced LDS-staged bf16 epilogue (see header comment)
    float* Lf = (float*)Ls;          // [64][132] f32 scratch, 33 KB
    const int rdrow = tid >> 3;      // 0..63
    const int rdc0 = (tid & 7) * 16; // 16-col span per thread
    const int wband = (wv >> 1) * 16;
#pragma unroll
    for (int mt = 0; mt < 4; mt++) {
      __syncthreads();  // K-loop reads / previous-round reads complete
#pragma unroll
      for (int nt = 0; nt < 4; nt++) {
        int col = wn + nt * 16 + l15;
#pragma unroll
        for (int rr = 0; rr < 4; rr++) {
          int rowl = wband + quad * 4 + rr;
          Lf[rowl * 132 + col] = acc[mt][nt][rr] + bvv[nt];
        }
      }
      __syncthreads();
      int gm = m0 + (rdrow >> 4) * 64 + mt * 16 + (rdrow & 15);
      u16 pk[16];
      if (epi == 2) {
#pragma unroll
        for (int j = 0; j < 16; j++)
          pk[j] = f2bf(gelu_t(Lf[rdrow * 132 + rdc0 + j]));
      } else {
#pragma unroll
        for (int j = 0; j < 16; j++)
          pk[j] = f2bf(Lf[rdrow * 132 + rdc0 + j]);
      }
      int gn0 = n0 + rdc0;
      size_t base;
      if (epi == 0) {
        // head-major: cols of this 16-span stay within one head, dd in {0,16}
        int part = gn0 >> 9, hh = (gn0 >> 5) & 15, dd = gn0 & 31;
        base = (((size_t)(part * 16 + hh) * 32768) + gm) * 32 + dd;
      } else {
        base = (size_t)gm * N + gn0;
      }
      *(short8*)(outb + base) = *(const short8*)pk;
      *(short8*)(outb + base + 8) = *(const short8*)(pk + 8);
    }
  } else {
    // fp32 + residual epilogues (epi 1 / 3), direct path
#pragma unroll
    for (int mt = 0; mt < 4; mt++) {
#pragma unroll
      for (int rr = 0; rr < 4; rr++) {
        int gm = m0 + wm + mt * 16 + quad * 4 + rr;
        size_t rowbase;
        if (epi == 1) {
          int tok = gm & 63, winin = (gm >> 6) & 63, bb = gm >> 12;
          int sr = (winin >> 3) * 8 + (tok >> 3);
          int sc = (winin & 7) * 8 + (tok & 7);
          int fr = (sr + SHIFT_) & 63, fc = (sc + SHIFT_) & 63;
          rowbase = ((size_t)bb * 4096 + fr * 64 + fc) * 512;
        } else {
          rowbase = (size_t)gm * 512;
        }
#pragma unroll
        for (int nt = 0; nt < 4; nt++) {
          int gn = n0 + wn + nt * 16 + l15;
          float val = acc[mt][nt][rr] + bvv[nt];
          size_t idx = rowbase + gn;
          outf[idx] = resf[idx] + val;
        }
      }
    }
  }
}

// ---------------- attention: one wave per (window, head) ----------------
// q/k/v: head-major [h][32768][32] bf16 (contiguous 64x32 tile per win,h)
__global__ __launch_bounds__(64) void attn(const u16* __restrict__ q, const u16* __restrict__ k,
                                           const u16* __restrict__ v, const float* __restrict__ tbl,
                                           u16* __restrict__ ctx) {
  __shared__ __attribute__((aligned(16))) u16 Pl[64 * 80];
  __shared__ __attribute__((aligned(16))) u16 Vt[32 * 72];  // V^T: [dim][token]
  __shared__ float tb[225];
  const int win = blockIdx.x, h = blockIdx.y;
  const int lane = threadIdx.x;
  const int l15 = lane & 15, quad = lane >> 4;

  for (int idx = lane; idx < 225; idx += 64) tb[idx] = tbl[idx * 16 + h];

  const size_t tilebase = ((size_t)h * 32768 + win * 64) * 32;
  const u16* qh = q + tilebase;
  const u16* kh = k + tilebase;
  const u16* vh = v + tilebase;

  // stage V transposed via fully-coalesced b128 loads
#pragma unroll
  for (int rnd = 0; rnd < 4; rnd++) {
    int t = rnd * 16 + (lane >> 2);
    int c = (lane & 3) * 8;
    short8 vrow = ld8(vh + t * 32 + c);
#pragma unroll
    for (int j = 0; j < 8; j++) Vt[(c + j) * 72 + t] = (u16)vrow[j];
  }

  short8 aq[4], bkf[4];
#pragma unroll
  for (int mt = 0; mt < 4; mt++) aq[mt] = ld8(qh + (mt * 16 + l15) * 32 + quad * 8);
#pragma unroll
  for (int nt = 0; nt < 4; nt++) bkf[nt] = ld8(kh + (nt * 16 + l15) * 32 + quad * 8);

  f32x4 zero4 = {0.f, 0.f, 0.f, 0.f};
  f32x4 s[4][4];
#pragma unroll
  for (int i = 0; i < 4; i++)
#pragma unroll
    for (int j = 0; j < 4; j++) s[i][j] = zero4;
#pragma unroll
  for (int mt = 0; mt < 4; mt++)
#pragma unroll
    for (int nt = 0; nt < 4; nt++)
      s[mt][nt] = __builtin_amdgcn_mfma_f32_16x16x32_bf16(aq[mt], bkf[nt], s[mt][nt], 0, 0, 0);

  __syncthreads();  // tb + Vt ready

  const int winin = win & 63;
  const int wrow0 = (winin >> 3) * 8, wcol0 = (winin & 7) * 8;
  int valc[4], ci[4], cj[4];
#pragma unroll
  for (int nt = 0; nt < 4; nt++) {
    int ct = nt * 16 + l15;
    ci[nt] = ct >> 3;
    cj[nt] = ct & 7;
    int rr_ = wrow0 + ci[nt], cc_ = wcol0 + cj[nt];
    valc[nt] = 3 * (rr_ < 56 ? 0 : (rr_ < 60 ? 1 : 2)) + (cc_ < 56 ? 0 : (cc_ < 60 ? 1 : 2));
  }
  const float scale = 0.17677669529663687f;  // 1/sqrt(32)
#pragma unroll
  for (int mt = 0; mt < 4; mt++) {
#pragma unroll
    for (int rr = 0; rr < 4; rr++) {
      int rt = mt * 16 + quad * 4 + rr;
      int i1 = rt >> 3, j1 = rt & 7;
      int rrow = wrow0 + i1, rcol = wcol0 + j1;
      int valr = 3 * (rrow < 56 ? 0 : (rrow < 60 ? 1 : 2)) + (rcol < 56 ? 0 : (rcol < 60 ? 1 : 2));
      float sv[4];
      float sum = 0.f;
      // scores are O(+-10): exp without max-subtraction is safe in fp32
#pragma unroll
      for (int nt = 0; nt < 4; nt++) {
        int idx = (i1 - ci[nt] + 7) * 15 + (j1 - cj[nt] + 7);
        float e = s[mt][nt][rr] * scale + tb[idx] + (valr == valc[nt] ? 0.f : -100.f);
        sv[nt] = __expf(e);
        sum += sv[nt];
      }
#pragma unroll
      for (int m = 1; m < 16; m <<= 1) sum += __shfl_xor(sum, m);
      float inv = 1.f / sum;
#pragma unroll
      for (int nt = 0; nt < 4; nt++) Pl[rt * 80 + nt * 16 + l15] = f2bf(sv[nt] * inv);
    }
  }
  __syncthreads();

  // O = P(64x64) @ V(64x32), V^T from LDS
  f32x4 o[4][2];
#pragma unroll
  for (int i = 0; i < 4; i++)
#pragma unroll
    for (int j = 0; j < 2; j++) o[i][j] = zero4;
#pragma unroll
  for (int kk = 0; kk < 2; kk++) {
    short8 bv2[2];
#pragma unroll
    for (int nt = 0; nt < 2; nt++)
      bv2[nt] = ld8(Vt + (nt * 16 + l15) * 72 + kk * 32 + quad * 8);
#pragma unroll
    for (int mt = 0; mt < 4; mt++) {
      short8 ap = ld8(Pl + (mt * 16 + l15) * 80 + kk * 32 + quad * 8);
#pragma unroll
      for (int nt = 0; nt < 2; nt++)
        o[mt][nt] = __builtin_amdgcn_mfma_f32_16x16x32_bf16(ap, bv2[nt], o[mt][nt], 0, 0, 0);
    }
  }
  const size_t cbase = (size_t)win * 64 * 512 + h * 32;
#pragma unroll
  for (int mt = 0; mt < 4; mt++)
#pragma unroll
    for (int rr = 0; rr < 4; rr++) {
      int rt = mt * 16 + quad * 4 + rr;
#pragma unroll
      for (int nt = 0; nt < 2; nt++)
        ctx[cbase + (size_t)rt * 512 + nt * 16 + l15] = f2bf(o[mt][nt][rr]);
    }
}

extern "C" void kernel_launch(void* const* d_in, const int* in_sizes, int n_in,
                              void* d_out, int out_size, void* d_ws, size_t ws_size,
                              hipStream_t stream) {
  const float* hs   = (const float*)d_in[0];
  const float* ln1g = (const float*)d_in[1];
  const float* ln1b = (const float*)d_in[2];
  const float* wq   = (const float*)d_in[3];
  const float* bq   = (const float*)d_in[4];
  const float* wk   = (const float*)d_in[5];
  const float* bk   = (const float*)d_in[6];
  const float* wvp  = (const float*)d_in[7];
  const float* bv   = (const float*)d_in[8];
  const float* tbl  = (const float*)d_in[9];
  const float* wo   = (const float*)d_in[10];
  const float* bo   = (const float*)d_in[11];
  const float* ln2g = (const float*)d_in[12];
  const float* ln2b = (const float*)d_in[13];
  const float* w1   = (const float*)d_in[14];
  const float* b1   = (const float*)d_in[15];
  const float* w2   = (const float*)d_in[16];
  const float* b2   = (const float*)d_in[17];
  float* out = (float*)d_out;
  u16* ws = (u16*)d_ws;

  const size_t S = (size_t)32768 * 512;
  u16* xw   = ws;          // LN1 out / ctx / LN2 out (bf16, S)
  u16* qb   = ws + S;      // Q head-major [16][32768][32]
  u16* kb   = ws + 2 * S;  // K head-major
  u16* vb   = ws + 3 * S;  // V head-major
  u16* y1   = ws + S;      // MLP intermediate (32768 x 2048 bf16, 4S) after attn
  u16* wt   = ws + 5 * S;  // transposed weights (bf16)
  u16* wqkvT = wt;         // 1536 x 512 (wq^T | wk^T | wv^T rows)
  u16* woT  = wt + 786432;
  u16* w1T  = wt + 1048576;
  u16* w2T  = wt + 2097152;
  float* bcat = (float*)(wt + 3145728);  // 1536 fp32
  float* hid = out;        // residual stream lives in d_out (fp32)

  // fused 4x 512x512 weight transpose (wq,wk,wv,wo) in one launch
  transp4<<<dim3(16, 16, 4), 256, 0, stream>>>(wq, wk, wvp, wo,
                                               wqkvT, wqkvT + 262144, wqkvT + 524288, woT);
  transp<<<dim3(64, 16), 256, 0, stream>>>(w1, w1T, 512, 2048);
  transp<<<dim3(16, 64), 256, 0, stream>>>(w2, w2T, 2048, 512);
  concat_bias<<<6, 256, 0, stream>>>(bq, bk, bv, bcat);

  ln_win<<<8192, 256, 0, stream>>>(hs, ln1g, ln1b, xw, 1);

  // fused QKV: (32768 x 512) @ (512 x 1536) -> head-major Q/K/V at ws+S
  gemm_tb<<<dim3(128, 12), 512, 0, stream>>>(xw, wqkvT, bcat, qb, nullptr, nullptr,
                                             32768, 1536, 512, 0);

  attn<<<dim3(512, 16), 64, 0, stream>>>(qb, kb, vb, tbl, xw);

  // hid = hs + window_reverse(ctx @ Wo + bo)   (fp32, into d_out)
  gemm_tb<<<dim3(128, 4), 512, 0, stream>>>(xw, woT, bo, nullptr, hid, hs,
                                            32768, 512, 512, 1);

  // LN2(hid) -> xw (bf16)
  ln_win<<<8192, 256, 0, stream>>>(hid, ln2g, ln2b, xw, 0);

  // y1 = gelu(LN2 @ w1 + b1), full M
  gemm_tb<<<dim3(128, 16), 512, 0, stream>>>(xw, w1T, b1, y1, nullptr, nullptr,
                                             32768, 2048, 512, 2);
  // out = hid + y1 @ w2T + b2  (fp32, in-place RMW on d_out)
  gemm_tb<<<dim3(128, 4), 512, 0, stream>>>(y1, w2T, b2, nullptr, out, hid,
                                            32768, 512, 2048, 3);
}